// Round 2
// baseline (3570.710 us; speedup 1.0000x reference)
//
#include <hip/hip_runtime.h>
#include <hip/hip_bf16.h>

// VQEmbedding straight-through forward, bf16-MFMA + exact-refine version.
//   z_e_x: [B=64, C=256, H=32, W=32] fp32, codebook: [K=1024, C=256] fp32
//   out: (z_q_x, z_q_x) both [B,C,H,W] fp32, concatenated flat.
//
// argmin_k ||x-c_k||^2 == argmin_k (||c_k||^2 - 2 x.c_k).
// Pipeline: A1 cnorm | A2 cb->bf16 | B mfma top-2 + flag margin<EPS
//           | C fp32 exact re-argmin of flagged pixels | D gather+write.
// Pixels with bf16 top-2 margin >= EPS=1.0 are provably stable (err sigma
// ~0.05, hard bound ~1.3, 14 sigma slack); the rest get exact fp32 rescan.

#define C_DIM 256
#define HW    1024
#define K_CODES 1024
#define OUT_OFF 16777216   // 64*256*32*32
#define EPS 1.0f

typedef short bf16x8 __attribute__((ext_vector_type(8)));
typedef float f32x4  __attribute__((ext_vector_type(4)));

// ws layout (bytes):            offset      size
//   cnorm   f32[1024]           0           4096
//   counter int                 4096        4
//   list    int[65536]          4352        262144
//   idxarr  int[65536]          266496      262144
//   cb16    short[1024*256]     528640      524288   (16B aligned)
#define WS_NEED 1052928u

__device__ __forceinline__ short f2bf(float f) {
    union { float f; unsigned u; } v; v.f = f;
    unsigned u = v.u + 0x7fffu + ((v.u >> 16) & 1u);   // RNE
    return (short)(u >> 16);
}

__global__ __launch_bounds__(256) void vq_cnorm_kernel(const float* __restrict__ cb,
                                                       float* __restrict__ cnorm) {
    int k = blockIdx.x * 256 + threadIdx.x;
    if (k >= K_CODES) return;
    const float4* row = reinterpret_cast<const float4*>(cb + (size_t)k * C_DIM);
    float s = 0.f;
#pragma unroll 8
    for (int u = 0; u < C_DIM / 4; ++u) {
        float4 v = row[u];
        s += v.x * v.x + v.y * v.y + v.z * v.z + v.w * v.w;
    }
    cnorm[k] = s;
}

__global__ __launch_bounds__(256) void vq_cvt_kernel(const float* __restrict__ cb,
                                                     short* __restrict__ cb16) {
    int base = blockIdx.x * 2048 + threadIdx.x * 8;
    float4 a = *reinterpret_cast<const float4*>(&cb[base]);
    float4 b = *reinterpret_cast<const float4*>(&cb[base + 4]);
    bf16x8 o;
    o[0] = f2bf(a.x); o[1] = f2bf(a.y); o[2] = f2bf(a.z); o[3] = f2bf(a.w);
    o[4] = f2bf(b.x); o[5] = f2bf(b.y); o[6] = f2bf(b.z); o[7] = f2bf(b.w);
    *reinterpret_cast<bf16x8*>(&cb16[base]) = o;
}

// Main MFMA kernel: block = 64 px (one b, contiguous hw span) x all 1024 codes
// in 16 tiles of 64. 4 waves in 2x2 (px-half x code-half) quadrants; each wave
// quadrant = 2x2 tiles of 16x16, K-loop 8 steps of 32 over d=256.
// Tracks per-pixel top-1 (value+idx) and top-2 (value) of bf16 distances.
__global__ __launch_bounds__(256, 2) void vq_mfma_kernel(const float* __restrict__ z,
                                                         const short* __restrict__ cb16,
                                                         const float* __restrict__ cnorm,
                                                         int* __restrict__ counter,
                                                         int* __restrict__ list,
                                                         int* __restrict__ idxarr) {
    // 264 = 256 + 8 pad: row stride 528 B = 33 x 16B slots (odd) -> the 16
    // rows of a fragment-read spread across all 8 bank-slots; 2-way only.
    __shared__ __align__(16) short Xs[64][264];   // 33.0 KB  [px][d] bf16
    __shared__ __align__(16) short Cs[64][264];   // 33.0 KB  [code][d] bf16
    __shared__ float cns[K_CODES];                // 4 KB
    __shared__ float sb1[2][64], sb2[2][64];      // cross-wave (wn) combine
    __shared__ int   si[2][64];

    const int t   = threadIdx.x;
    const int b   = blockIdx.x >> 4;
    const int hw0 = (blockIdx.x & 15) << 6;
    const size_t zbase = (size_t)b * (C_DIM * HW) + hw0;

    // --- stage X: fp32 global (coalesced float4 over px) -> bf16 LDS [px][d]
#pragma unroll
    for (int r = 0; r < 16; ++r) {
        int id  = t + 256 * r;        // 0..4095
        int c   = id >> 4;            // 0..255
        int px4 = (id & 15) << 2;
        float4 v = *reinterpret_cast<const float4*>(&z[zbase + (size_t)c * HW + px4]);
        Xs[px4 + 0][c] = f2bf(v.x);
        Xs[px4 + 1][c] = f2bf(v.y);
        Xs[px4 + 2][c] = f2bf(v.z);
        Xs[px4 + 3][c] = f2bf(v.w);
    }
#pragma unroll
    for (int r = 0; r < 4; ++r) cns[t + 256 * r] = cnorm[t + 256 * r];

    const int lane = t & 63;
    const int w    = t >> 6;
    const int wm   = w >> 1;      // px half
    const int wn   = w & 1;       // code half
    const int l15  = lane & 15;
    const int l4   = lane >> 4;

    float b1[8], b2[8]; int i1[8];
#pragma unroll
    for (int s = 0; s < 8; ++s) { b1[s] = 3.4e38f; b2[s] = 3.4e38f; i1[s] = 0; }

    const int arow0 = 32 * wm + l15;
    const int brow0 = 32 * wn + l15;

    for (int kt = 0; kt < 16; ++kt) {
        __syncthreads();   // prior pass readers done (also covers X staging on kt=0)
        // stage Cs tile: 64 codes x 256 d bf16 from precomputed cb16
        const short* csrc = cb16 + (size_t)(kt * 64) * C_DIM;
#pragma unroll
        for (int r = 0; r < 8; ++r) {
            int id   = t + 256 * r;       // 0..2047
            int code = id >> 5;
            int dp   = (id & 31) << 3;
            *reinterpret_cast<bf16x8*>(&Cs[code][dp]) =
                *reinterpret_cast<const bf16x8*>(&csrc[code * C_DIM + dp]);
        }
        __syncthreads();

        f32x4 acc00 = 0.f, acc01 = 0.f, acc10 = 0.f, acc11 = 0.f;
#pragma unroll
        for (int ks = 0; ks < 8; ++ks) {
            int dsl = ks * 32 + l4 * 8;
            bf16x8 a0 = *reinterpret_cast<const bf16x8*>(&Xs[arow0][dsl]);
            bf16x8 a1 = *reinterpret_cast<const bf16x8*>(&Xs[arow0 + 16][dsl]);
            bf16x8 c0 = *reinterpret_cast<const bf16x8*>(&Cs[brow0][dsl]);
            bf16x8 c1 = *reinterpret_cast<const bf16x8*>(&Cs[brow0 + 16][dsl]);
            acc00 = __builtin_amdgcn_mfma_f32_16x16x32_bf16(a0, c0, acc00, 0, 0, 0);
            acc01 = __builtin_amdgcn_mfma_f32_16x16x32_bf16(a0, c1, acc01, 0, 0, 0);
            acc10 = __builtin_amdgcn_mfma_f32_16x16x32_bf16(a1, c0, acc10, 0, 0, 0);
            acc11 = __builtin_amdgcn_mfma_f32_16x16x32_bf16(a1, c1, acc11, 0, 0, 0);
        }

        // dist = ||c||^2 - 2 x.c ; D layout: row(px_local)=(l>>4)*4+reg, col(code)=l&15
#pragma unroll
        for (int mi = 0; mi < 2; ++mi) {
#pragma unroll
            for (int nj = 0; nj < 2; ++nj) {
                int code = kt * 64 + 32 * wn + 16 * nj + l15;
                float cnv = cns[code];
                f32x4 a = (mi == 0) ? ((nj == 0) ? acc00 : acc01)
                                    : ((nj == 0) ? acc10 : acc11);
#pragma unroll
                for (int reg = 0; reg < 4; ++reg) {
                    float d = cnv - 2.f * a[reg];
                    int s = mi * 4 + reg;
                    if (d < b1[s]) { b2[s] = b1[s]; b1[s] = d; i1[s] = code; }
                    else if (d < b2[s]) b2[s] = d;
                }
            }
        }
    }

    // reduce top-2 across the 16 code-lanes (same l4 group), lowest-idx tie-break
#pragma unroll
    for (int s = 0; s < 8; ++s) {
        float v1 = b1[s], v2 = b2[s]; int ii = i1[s];
#pragma unroll
        for (int m = 1; m < 16; m <<= 1) {
            float o1 = __shfl_xor(v1, m, 16);
            float o2 = __shfl_xor(v2, m, 16);
            int   oi = __shfl_xor(ii, m, 16);
            if (o1 < v1 || (o1 == v1 && oi < ii)) { v2 = fminf(v1, o2); v1 = o1; ii = oi; }
            else { v2 = fminf(v2, o1); }
        }
        if (l15 == 0) {
            int mi = s >> 2, reg = s & 3;
            int px = 32 * wm + 16 * mi + l4 * 4 + reg;
            sb1[wn][px] = v1; sb2[wn][px] = v2; si[wn][px] = ii;
        }
    }
    __syncthreads();

    // combine the two code-halves, write idx, flag small-margin pixels
    if (t < 64) {
        float a1v = sb1[0][t], a2v = sb2[0][t]; int ai = si[0][t];
        float c1v = sb1[1][t], c2v = sb2[1][t]; int ci = si[1][t];
        float win, sec; int iw;
        if (c1v < a1v || (c1v == a1v && ci < ai)) {
            win = c1v; iw = ci; sec = fminf(a1v, c2v);
        } else {
            win = a1v; iw = ai; sec = fminf(a2v, c1v);
        }
        int gp = blockIdx.x * 64 + t;
        idxarr[gp] = iw;
        if (sec - win < EPS) {
            int p = atomicAdd(counter, 1);
            list[p] = gp;
        }
    }
}

// Exact fp32 re-argmin over all 1024 codes for flagged pixels; fixes idxarr.
__global__ __launch_bounds__(256) void vq_refine_kernel(const float* __restrict__ z,
                                                        const float* __restrict__ cb,
                                                        const float* __restrict__ cnorm,
                                                        const int* __restrict__ counter,
                                                        const int* __restrict__ list,
                                                        int* __restrict__ idxarr) {
    __shared__ float xl[256];
    __shared__ float rd[256];
    __shared__ int   ri[256];
    const int t = threadIdx.x;
    int cnt = counter[0];
    for (int li = blockIdx.x; li < cnt; li += gridDim.x) {
        int gp = list[li];
        int b = gp >> 10, hw = gp & 1023;
        __syncthreads();   // protect xl/rd/ri reuse across iterations
        xl[t] = z[(size_t)b * (C_DIM * HW) + (size_t)t * HW + hw];
        __syncthreads();
        float bd = 3.4e38f; int bi = 0;
#pragma unroll
        for (int j = 0; j < 4; ++j) {
            int k = t + 256 * j;   // ascending per thread
            const float4* cr = reinterpret_cast<const float4*>(cb + (size_t)k * C_DIM);
            float s0 = 0.f, s1 = 0.f, s2 = 0.f, s3 = 0.f;
            for (int d4 = 0; d4 < 64; ++d4) {
                float4 cv = cr[d4];
                s0 = fmaf(xl[4 * d4 + 0], cv.x, s0);
                s1 = fmaf(xl[4 * d4 + 1], cv.y, s1);
                s2 = fmaf(xl[4 * d4 + 2], cv.z, s2);
                s3 = fmaf(xl[4 * d4 + 3], cv.w, s3);
            }
            float dist = cnorm[k] - 2.f * ((s0 + s1) + (s2 + s3));
            if (dist < bd) { bd = dist; bi = k; }
        }
        rd[t] = bd; ri[t] = bi;
        __syncthreads();
        for (int s = 128; s > 0; s >>= 1) {
            if (t < s) {
                float o = rd[t + s]; int oi = ri[t + s];
                if (o < rd[t] || (o == rd[t] && oi < ri[t])) { rd[t] = o; ri[t] = oi; }
            }
            __syncthreads();
        }
        if (t == 0) idxarr[gp] = ri[0];
    }
}

// Gather final codes and write both outputs (coalesced 256B spans per channel).
__global__ __launch_bounds__(256) void vq_gather_kernel(const float* __restrict__ cb,
                                                        const int* __restrict__ idxarr,
                                                        float* __restrict__ out) {
    const int t   = threadIdx.x;
    const int b   = blockIdx.x >> 4;
    const int hw0 = (blockIdx.x & 15) << 6;
    const int px  = t & 63;
    const int c0  = t >> 6;
    const int code = idxarr[blockIdx.x * 64 + px];
    const float* crow = cb + (size_t)code * C_DIM;
    const size_t obase = (size_t)b * (C_DIM * HW) + hw0 + px;
#pragma unroll 4
    for (int c = c0; c < C_DIM; c += 4) {
        float v = crow[c];
        out[obase + (size_t)c * HW] = v;
        out[obase + (size_t)c * HW + OUT_OFF] = v;
    }
}

// ---------------- fallback (round-1 exact fp32 kernel, needs only 4KB ws) ----
__global__ __launch_bounds__(256, 4) void vq_main_kernel(const float* __restrict__ z,
                                                         const float* __restrict__ cb,
                                                         const float* __restrict__ cnorm,
                                                         float* __restrict__ out) {
    __shared__ float Xs[64][64];
    __shared__ float Bs[64][68];
    __shared__ float cns[K_CODES];
    __shared__ int   idxs[64];

    const int t  = threadIdx.x;
    const int tx = t & 15;
    const int ty = t >> 4;
    const int b   = blockIdx.x >> 4;
    const int hw0 = (blockIdx.x & 15) << 6;
    const size_t zbase = (size_t)b * (C_DIM * HW) + hw0;

#pragma unroll
    for (int r = 0; r < 4; ++r) cns[t + 256 * r] = cnorm[t + 256 * r];

    float best[4];
    int   bidx[4];
#pragma unroll
    for (int i = 0; i < 4; ++i) { best[i] = 3.4e38f; bidx[i] = 0; }

    for (int kt = 0; kt < 16; ++kt) {
        float acc[4][4];
#pragma unroll
        for (int i = 0; i < 4; ++i)
#pragma unroll
            for (int j = 0; j < 4; ++j) acc[i][j] = 0.f;

        for (int cc = 0; cc < 4; ++cc) {
            const int c0g = cc * 64;
            __syncthreads();
#pragma unroll
            for (int r = 0; r < 4; ++r) {
                int c   = (t >> 4) + 16 * r;
                int px4 = (t & 15) * 4;
                *reinterpret_cast<float4*>(&Xs[c][px4]) =
                    *reinterpret_cast<const float4*>(&z[zbase + (size_t)(c0g + c) * HW + px4]);
                int k  = (t >> 4) + 16 * r;
                int c4 = (t & 15) * 4;
                *reinterpret_cast<float4*>(&Bs[k][c4]) =
                    *reinterpret_cast<const float4*>(&cb[(size_t)(kt * 64 + k) * C_DIM + c0g + c4]);
            }
            __syncthreads();

#pragma unroll
            for (int c0 = 0; c0 < 64; c0 += 4) {
                float4 xv[4], bv[4];
#pragma unroll
                for (int s = 0; s < 4; ++s)
                    xv[s] = *reinterpret_cast<const float4*>(&Xs[c0 + s][4 * ty]);
#pragma unroll
                for (int j = 0; j < 4; ++j)
                    bv[j] = *reinterpret_cast<const float4*>(&Bs[16 * j + tx][c0]);
#pragma unroll
                for (int i = 0; i < 4; ++i) {
#pragma unroll
                    for (int j = 0; j < 4; ++j) {
                        float xi0 = (i == 0) ? xv[0].x : (i == 1) ? xv[0].y : (i == 2) ? xv[0].z : xv[0].w;
                        float xi1 = (i == 0) ? xv[1].x : (i == 1) ? xv[1].y : (i == 2) ? xv[1].z : xv[1].w;
                        float xi2 = (i == 0) ? xv[2].x : (i == 1) ? xv[2].y : (i == 2) ? xv[2].z : xv[2].w;
                        float xi3 = (i == 0) ? xv[3].x : (i == 1) ? xv[3].y : (i == 2) ? xv[3].z : xv[3].w;
                        acc[i][j] = fmaf(xi0, bv[j].x,
                                    fmaf(xi1, bv[j].y,
                                    fmaf(xi2, bv[j].z,
                                    fmaf(xi3, bv[j].w, acc[i][j]))));
                    }
                }
            }
        }

#pragma unroll
        for (int j = 0; j < 4; ++j) {
            int kg = kt * 64 + 16 * j + tx;
            float cnv = cns[kg];
#pragma unroll
            for (int i = 0; i < 4; ++i) {
                float d = cnv - 2.f * acc[i][j];
                if (d < best[i]) { best[i] = d; bidx[i] = kg; }
            }
        }
    }

#pragma unroll
    for (int i = 0; i < 4; ++i) {
#pragma unroll
        for (int off = 8; off >= 1; off >>= 1) {
            float od = __shfl_xor(best[i], off, 16);
            int   oi = __shfl_xor(bidx[i], off, 16);
            if (od < best[i] || (od == best[i] && oi < bidx[i])) { best[i] = od; bidx[i] = oi; }
        }
        if (tx == 0) idxs[4 * ty + i] = bidx[i];
    }
    __syncthreads();

    const int px = t & 63;
    const int c0 = t >> 6;
    const int code = idxs[px];
    const float* crow = cb + (size_t)code * C_DIM;
    const size_t obase = (size_t)b * (C_DIM * HW) + hw0 + px;
#pragma unroll 4
    for (int c = c0; c < C_DIM; c += 4) {
        float v = crow[c];
        out[obase + (size_t)c * HW] = v;
        out[obase + (size_t)c * HW + OUT_OFF] = v;
    }
}

extern "C" void kernel_launch(void* const* d_in, const int* in_sizes, int n_in,
                              void* d_out, int out_size, void* d_ws, size_t ws_size,
                              hipStream_t stream) {
    const float* z  = (const float*)d_in[0];
    const float* cb = (const float*)d_in[1];
    float* out = (float*)d_out;

    float* cnorm  = (float*)d_ws;                          // 4096 B
    int*   counter = (int*)((char*)d_ws + 4096);
    int*   list    = (int*)((char*)d_ws + 4352);
    int*   idxarr  = (int*)((char*)d_ws + 266496);
    short* cb16    = (short*)((char*)d_ws + 528640);

    vq_cnorm_kernel<<<K_CODES / 256, 256, 0, stream>>>(cb, cnorm);

    if (ws_size >= WS_NEED) {
        vq_cvt_kernel<<<128, 256, 0, stream>>>(cb, cb16);
        hipMemsetAsync(counter, 0, sizeof(int), stream);
        vq_mfma_kernel<<<1024, 256, 0, stream>>>(z, cb16, cnorm, counter, list, idxarr);
        vq_refine_kernel<<<256, 256, 0, stream>>>(z, cb, cnorm, counter, list, idxarr);
        vq_gather_kernel<<<1024, 256, 0, stream>>>(cb, idxarr, out);
    } else {
        vq_main_kernel<<<1024, 256, 0, stream>>>(z, cb, cnorm, out);
    }
}

// Round 3
// 635.472 us; speedup vs baseline: 5.6190x; 5.6190x over previous
//
#include <hip/hip_runtime.h>
#include <hip/hip_bf16.h>

// VQEmbedding straight-through forward, bf16-MFMA + top-3 margin + exact-refine.
//   z_e_x: [B=64, C=256, H=32, W=32] fp32, codebook: [K=1024, C=256] fp32
//   out: (z_q_x, z_q_x) both [B,C,H,W] fp32, concatenated flat.
//
// argmin_k ||x-c_k||^2 == argmin_k (||c_k||^2 - 2 x.c_k).
// Pipeline: A1 cnorm | A2 cb->bf16 | B mfma top-3 + classify
//           | C1 pair-compare (2 candidates, fp32) | C2 full rescan (rare)
//           | D gather+write.
// bf16 distance error sigma ~0.11, EPS=1.0 is ~9 sigma. A pixel's true argmin
// must be a code within EPS of the bf16 top-1:
//   gap13 < EPS  -> >=3 candidates -> full fp32 rescan  (~0.5% of pixels)
//   gap12 < EPS  -> exactly 2 candidates -> fp32 pair compare (~9%)
//   else         -> bf16 winner provably exact.

#define C_DIM 256
#define HW    1024
#define K_CODES 1024
#define OUT_OFF 16777216   // 64*256*32*32
#define EPS 1.0f

typedef short bf16x8 __attribute__((ext_vector_type(8)));
typedef float f32x4  __attribute__((ext_vector_type(4)));

// ws layout (bytes, all 16B aligned):
//   cnorm  f32[1024]        0        4096
//   cnts   int[4]           4096     16    ([0]=pairs, [1]=rescans)
//   list   int[65536]       4112     262144  (pairs grow from 0, rescans from top)
//   idxarr int[65536]       266256   262144
//   cb16   short[1024*256]  528400   524288
#define WS_CNORM 0
#define WS_CNTS  4096
#define WS_LIST  4112
#define WS_IDX   266256
#define WS_CB16  528400
#define WS_NEED  1052688u

__device__ __forceinline__ short f2bf(float f) {
    union { float f; unsigned u; } v; v.f = f;
    unsigned u = v.u + 0x7fffu + ((v.u >> 16) & 1u);   // RNE
    return (short)(u >> 16);
}

__global__ __launch_bounds__(256) void vq_cnorm_kernel(const float* __restrict__ cb,
                                                       float* __restrict__ cnorm) {
    int k = blockIdx.x * 256 + threadIdx.x;
    if (k >= K_CODES) return;
    const float4* row = reinterpret_cast<const float4*>(cb + (size_t)k * C_DIM);
    float s = 0.f;
#pragma unroll 8
    for (int u = 0; u < C_DIM / 4; ++u) {
        float4 v = row[u];
        s += v.x * v.x + v.y * v.y + v.z * v.z + v.w * v.w;
    }
    cnorm[k] = s;
}

__global__ __launch_bounds__(256) void vq_cvt_kernel(const float* __restrict__ cb,
                                                     short* __restrict__ cb16) {
    int base = blockIdx.x * 2048 + threadIdx.x * 8;
    float4 a = *reinterpret_cast<const float4*>(&cb[base]);
    float4 b = *reinterpret_cast<const float4*>(&cb[base + 4]);
    bf16x8 o;
    o[0] = f2bf(a.x); o[1] = f2bf(a.y); o[2] = f2bf(a.z); o[3] = f2bf(a.w);
    o[4] = f2bf(b.x); o[5] = f2bf(b.y); o[6] = f2bf(b.z); o[7] = f2bf(b.w);
    *reinterpret_cast<bf16x8*>(&cb16[base]) = o;
}

// Main MFMA kernel: block = 64 px x all 1024 codes in 16 tiles of 64.
// 4 waves in 2x2 (px-half x code-half) quadrants; K-loop 8 steps of 32 over d.
// Tracks per-pixel top-3 distances (+ top-2 indices) of bf16 distances.
__global__ __launch_bounds__(256, 2) void vq_mfma_kernel(const float* __restrict__ z,
                                                         const short* __restrict__ cb16,
                                                         const float* __restrict__ cnorm,
                                                         int* __restrict__ cnts,
                                                         int* __restrict__ list,
                                                         int* __restrict__ idxarr) {
    // 264 = 256 + 8 pad: row stride 528 B -> fragment reads are 2-way (free).
    __shared__ __align__(16) short Xs[64][264];
    __shared__ __align__(16) short Cs[64][264];
    __shared__ float cns[K_CODES];
    __shared__ float sb1[2][64], sb2[2][64], sb3[2][64];
    __shared__ int   si1[2][64], si2[2][64];

    const int t   = threadIdx.x;
    const int b   = blockIdx.x >> 4;
    const int hw0 = (blockIdx.x & 15) << 6;
    const size_t zbase = (size_t)b * (C_DIM * HW) + hw0;

    // stage X: fp32 global (coalesced float4 over px) -> bf16 LDS [px][d]
#pragma unroll
    for (int r = 0; r < 16; ++r) {
        int id  = t + 256 * r;
        int c   = id >> 4;
        int px4 = (id & 15) << 2;
        float4 v = *reinterpret_cast<const float4*>(&z[zbase + (size_t)c * HW + px4]);
        Xs[px4 + 0][c] = f2bf(v.x);
        Xs[px4 + 1][c] = f2bf(v.y);
        Xs[px4 + 2][c] = f2bf(v.z);
        Xs[px4 + 3][c] = f2bf(v.w);
    }
#pragma unroll
    for (int r = 0; r < 4; ++r) cns[t + 256 * r] = cnorm[t + 256 * r];

    const int lane = t & 63;
    const int w    = t >> 6;
    const int wm   = w >> 1;      // px half
    const int wn   = w & 1;       // code half
    const int l15  = lane & 15;
    const int l4   = lane >> 4;

    float b1[8], b2[8], b3[8]; int i1[8], i2[8];
#pragma unroll
    for (int s = 0; s < 8; ++s) {
        b1[s] = 3.4e38f; b2[s] = 3.4e38f; b3[s] = 3.4e38f; i1[s] = 0; i2[s] = 0;
    }

    const int arow0 = 32 * wm + l15;
    const int brow0 = 32 * wn + l15;

    for (int kt = 0; kt < 16; ++kt) {
        __syncthreads();
        const short* csrc = cb16 + (size_t)(kt * 64) * C_DIM;
#pragma unroll
        for (int r = 0; r < 8; ++r) {
            int id   = t + 256 * r;
            int code = id >> 5;
            int dp   = (id & 31) << 3;
            *reinterpret_cast<bf16x8*>(&Cs[code][dp]) =
                *reinterpret_cast<const bf16x8*>(&csrc[code * C_DIM + dp]);
        }
        __syncthreads();

        f32x4 acc00 = 0.f, acc01 = 0.f, acc10 = 0.f, acc11 = 0.f;
#pragma unroll
        for (int ks = 0; ks < 8; ++ks) {
            int dsl = ks * 32 + l4 * 8;
            bf16x8 a0 = *reinterpret_cast<const bf16x8*>(&Xs[arow0][dsl]);
            bf16x8 a1 = *reinterpret_cast<const bf16x8*>(&Xs[arow0 + 16][dsl]);
            bf16x8 c0 = *reinterpret_cast<const bf16x8*>(&Cs[brow0][dsl]);
            bf16x8 c1 = *reinterpret_cast<const bf16x8*>(&Cs[brow0 + 16][dsl]);
            acc00 = __builtin_amdgcn_mfma_f32_16x16x32_bf16(a0, c0, acc00, 0, 0, 0);
            acc01 = __builtin_amdgcn_mfma_f32_16x16x32_bf16(a0, c1, acc01, 0, 0, 0);
            acc10 = __builtin_amdgcn_mfma_f32_16x16x32_bf16(a1, c0, acc10, 0, 0, 0);
            acc11 = __builtin_amdgcn_mfma_f32_16x16x32_bf16(a1, c1, acc11, 0, 0, 0);
        }

        // dist = ||c||^2 - 2 x.c ; D layout: row(px)=(l>>4)*4+reg, col(code)=l&15
#pragma unroll
        for (int mi = 0; mi < 2; ++mi) {
#pragma unroll
            for (int nj = 0; nj < 2; ++nj) {
                int code = kt * 64 + 32 * wn + 16 * nj + l15;
                float cnv = cns[code];
                f32x4 a = (mi == 0) ? ((nj == 0) ? acc00 : acc01)
                                    : ((nj == 0) ? acc10 : acc11);
#pragma unroll
                for (int reg = 0; reg < 4; ++reg) {
                    float d = fmaf(-2.f, a[reg], cnv);
                    int s = mi * 4 + reg;
                    bool lt1 = d < b1[s];
                    bool lt2 = d < b2[s];
                    bool lt3 = d < b3[s];
                    b3[s] = lt2 ? b2[s] : (lt3 ? d : b3[s]);
                    i2[s] = lt1 ? i1[s] : (lt2 ? code : i2[s]);
                    b2[s] = lt1 ? b1[s] : (lt2 ? d : b2[s]);
                    i1[s] = lt1 ? code : i1[s];
                    b1[s] = lt1 ? d : b1[s];
                }
            }
        }
    }

    // reduce top-3 across the 16 code-lanes (same l4 group), lowest-idx ties
#pragma unroll
    for (int s = 0; s < 8; ++s) {
        float v1 = b1[s], v2 = b2[s], v3 = b3[s]; int j1 = i1[s], j2 = i2[s];
#pragma unroll
        for (int m = 1; m < 16; m <<= 1) {
            float o1 = __shfl_xor(v1, m, 16);
            float o2 = __shfl_xor(v2, m, 16);
            float o3 = __shfl_xor(v3, m, 16);
            int  oj1 = __shfl_xor(j1, m, 16);
            int  oj2 = __shfl_xor(j2, m, 16);
            bool sw = (o1 < v1) || (o1 == v1 && oj1 < j1);
            float A1 = sw ? o1 : v1, A2 = sw ? o2 : v2, A3 = sw ? o3 : v3;
            int  Aj1 = sw ? oj1 : j1, Aj2 = sw ? oj2 : j2;
            float B1 = sw ? v1 : o1, B2 = sw ? v2 : o2;
            float B3 = sw ? v3 : o3;
            int  Bj1 = sw ? j1 : oj1;
            bool t2B = (B1 < A2) || (B1 == A2 && Bj1 < Aj2);
            v1 = A1; j1 = Aj1;
            v2 = t2B ? B1 : A2; j2 = t2B ? Bj1 : Aj2;
            v3 = t2B ? fminf(A2, B2) : fminf(A3, B1);
        }
        if (l15 == 0) {
            int mi = s >> 2, reg = s & 3;
            int px = 32 * wm + 16 * mi + l4 * 4 + reg;
            sb1[wn][px] = v1; sb2[wn][px] = v2; sb3[wn][px] = v3;
            si1[wn][px] = j1; si2[wn][px] = j2;
        }
    }
    __syncthreads();

    // combine the two code-halves, write idx, classify margin
    if (t < 64) {
        float a1v = sb1[0][t], a2v = sb2[0][t], a3v = sb3[0][t];
        int   aj1 = si1[0][t], aj2 = si2[0][t];
        float c1v = sb1[1][t], c2v = sb2[1][t], c3v = sb3[1][t];
        int   cj1 = si1[1][t], cj2 = si2[1][t];
        bool sw = (c1v < a1v) || (c1v == a1v && cj1 < aj1);
        float A1 = sw ? c1v : a1v, A2 = sw ? c2v : a2v, A3 = sw ? c3v : a3v;
        int  Aj1 = sw ? cj1 : aj1, Aj2 = sw ? cj2 : aj2;
        float B1 = sw ? a1v : c1v, B2 = sw ? a2v : c2v;
        float B3 = sw ? a3v : c3v;
        int  Bj1 = sw ? aj1 : cj1;
        bool t2B = (B1 < A2) || (B1 == A2 && Bj1 < Aj2);
        float v1 = A1;            int j1 = Aj1;
        float v2 = t2B ? B1 : A2; int j2 = t2B ? Bj1 : Aj2;
        float v3 = t2B ? fminf(A2, B2) : fminf(A3, B1);

        int gp = blockIdx.x * 64 + t;
        idxarr[gp] = j1;
        if (v3 - v1 < EPS) {            // >=3 candidates: full rescan (rare)
            int p = atomicAdd(&cnts[1], 1);
            list[65535 - p] = gp;
        } else if (v2 - v1 < EPS) {     // exactly 2 candidates: pair compare
            int p = atomicAdd(&cnts[0], 1);
            list[p] = gp | (j2 << 16);
        }
    }
}

// Exact fp32 compare of the two candidate codes; one wave per pixel.
__global__ __launch_bounds__(256) void vq_pair_kernel(const float* __restrict__ z,
                                                      const float* __restrict__ cb,
                                                      const float* __restrict__ cnorm,
                                                      const int* __restrict__ cnts,
                                                      const int* __restrict__ list,
                                                      int* __restrict__ idxarr) {
    const int lane = threadIdx.x & 63;
    const int wid  = (blockIdx.x * 256 + threadIdx.x) >> 6;
    const int nw   = gridDim.x * 4;
    const int np   = cnts[0];
    for (int p = wid; p < np; p += nw) {
        int e  = list[p];
        int px = e & 0xFFFF;
        int k2 = (e >> 16) & 0x3FF;
        int k1 = idxarr[px];
        int b = px >> 10, hw = px & 1023;
        const float* xb = z + (size_t)b * (C_DIM * HW) + hw;
        float x0 = xb[(size_t)(4 * lane + 0) * HW];
        float x1 = xb[(size_t)(4 * lane + 1) * HW];
        float x2 = xb[(size_t)(4 * lane + 2) * HW];
        float x3 = xb[(size_t)(4 * lane + 3) * HW];
        float4 a1 = *reinterpret_cast<const float4*>(&cb[(size_t)k1 * C_DIM + 4 * lane]);
        float4 a2 = *reinterpret_cast<const float4*>(&cb[(size_t)k2 * C_DIM + 4 * lane]);
        float s1 = fmaf(x0, a1.x, fmaf(x1, a1.y, fmaf(x2, a1.z, x3 * a1.w)));
        float s2 = fmaf(x0, a2.x, fmaf(x1, a2.y, fmaf(x2, a2.z, x3 * a2.w)));
#pragma unroll
        for (int m = 1; m < 64; m <<= 1) {
            s1 += __shfl_xor(s1, m, 64);
            s2 += __shfl_xor(s2, m, 64);
        }
        if (lane == 0) {
            float d1 = fmaf(-2.f, s1, cnorm[k1]);
            float d2 = fmaf(-2.f, s2, cnorm[k2]);
            if (d2 < d1 || (d2 == d1 && k2 < k1)) idxarr[px] = k2;
        }
    }
}

// Exact fp32 re-argmin over all 1024 codes; one block per flagged pixel.
__global__ __launch_bounds__(256) void vq_rescan_kernel(const float* __restrict__ z,
                                                        const float* __restrict__ cb,
                                                        const float* __restrict__ cnorm,
                                                        const int* __restrict__ cnts,
                                                        const int* __restrict__ list,
                                                        int* __restrict__ idxarr) {
    __shared__ float xl[256];
    __shared__ float rd4[4];
    __shared__ int   ri4[4];
    const int t = threadIdx.x;
    const int nr = cnts[1];
    for (int q = blockIdx.x; q < nr; q += gridDim.x) {
        int gp = list[65535 - q];
        int b = gp >> 10, hw = gp & 1023;
        __syncthreads();
        xl[t] = z[(size_t)b * (C_DIM * HW) + (size_t)t * HW + hw];
        __syncthreads();
        float bd = 3.4e38f; int bi = 0;
#pragma unroll
        for (int j = 0; j < 4; ++j) {
            int k = t + 256 * j;   // ascending per thread -> strict < keeps lowest
            const float4* cr = reinterpret_cast<const float4*>(cb + (size_t)k * C_DIM);
            float s0 = 0.f, s1 = 0.f, s2 = 0.f, s3 = 0.f;
            for (int d4 = 0; d4 < 64; ++d4) {
                float4 cv = cr[d4];
                s0 = fmaf(xl[4 * d4 + 0], cv.x, s0);
                s1 = fmaf(xl[4 * d4 + 1], cv.y, s1);
                s2 = fmaf(xl[4 * d4 + 2], cv.z, s2);
                s3 = fmaf(xl[4 * d4 + 3], cv.w, s3);
            }
            float dist = fmaf(-2.f, (s0 + s1) + (s2 + s3), cnorm[k]);
            if (dist < bd) { bd = dist; bi = k; }
        }
#pragma unroll
        for (int m = 1; m < 64; m <<= 1) {
            float od = __shfl_xor(bd, m, 64);
            int   oi = __shfl_xor(bi, m, 64);
            if (od < bd || (od == bd && oi < bi)) { bd = od; bi = oi; }
        }
        if ((t & 63) == 0) { rd4[t >> 6] = bd; ri4[t >> 6] = bi; }
        __syncthreads();
        if (t == 0) {
            float fb = rd4[0]; int fi = ri4[0];
#pragma unroll
            for (int u = 1; u < 4; ++u) {
                if (rd4[u] < fb || (rd4[u] == fb && ri4[u] < fi)) { fb = rd4[u]; fi = ri4[u]; }
            }
            idxarr[gp] = fi;
        }
        __syncthreads();
    }
}

// Gather final codes and write both outputs.
__global__ __launch_bounds__(256) void vq_gather_kernel(const float* __restrict__ cb,
                                                        const int* __restrict__ idxarr,
                                                        float* __restrict__ out) {
    const int t   = threadIdx.x;
    const int b   = blockIdx.x >> 4;
    const int hw0 = (blockIdx.x & 15) << 6;
    const int px  = t & 63;
    const int c0  = t >> 6;
    const int code = idxarr[blockIdx.x * 64 + px];
    const float* crow = cb + (size_t)code * C_DIM;
    const size_t obase = (size_t)b * (C_DIM * HW) + hw0 + px;
#pragma unroll 4
    for (int c = c0; c < C_DIM; c += 4) {
        float v = crow[c];
        out[obase + (size_t)c * HW] = v;
        out[obase + (size_t)c * HW + OUT_OFF] = v;
    }
}

// ---------------- fallback (round-1 exact fp32 kernel, needs only 4KB ws) ----
__global__ __launch_bounds__(256, 4) void vq_main_kernel(const float* __restrict__ z,
                                                         const float* __restrict__ cb,
                                                         const float* __restrict__ cnorm,
                                                         float* __restrict__ out) {
    __shared__ float Xs[64][64];
    __shared__ float Bs[64][68];
    __shared__ float cns[K_CODES];
    __shared__ int   idxs[64];

    const int t  = threadIdx.x;
    const int tx = t & 15;
    const int ty = t >> 4;
    const int b   = blockIdx.x >> 4;
    const int hw0 = (blockIdx.x & 15) << 6;
    const size_t zbase = (size_t)b * (C_DIM * HW) + hw0;

#pragma unroll
    for (int r = 0; r < 4; ++r) cns[t + 256 * r] = cnorm[t + 256 * r];

    float best[4];
    int   bidx[4];
#pragma unroll
    for (int i = 0; i < 4; ++i) { best[i] = 3.4e38f; bidx[i] = 0; }

    for (int kt = 0; kt < 16; ++kt) {
        float acc[4][4];
#pragma unroll
        for (int i = 0; i < 4; ++i)
#pragma unroll
            for (int j = 0; j < 4; ++j) acc[i][j] = 0.f;

        for (int cc = 0; cc < 4; ++cc) {
            const int c0g = cc * 64;
            __syncthreads();
#pragma unroll
            for (int r = 0; r < 4; ++r) {
                int c   = (t >> 4) + 16 * r;
                int px4 = (t & 15) * 4;
                *reinterpret_cast<float4*>(&Xs[c][px4]) =
                    *reinterpret_cast<const float4*>(&z[zbase + (size_t)(c0g + c) * HW + px4]);
                int k  = (t >> 4) + 16 * r;
                int c4 = (t & 15) * 4;
                *reinterpret_cast<float4*>(&Bs[k][c4]) =
                    *reinterpret_cast<const float4*>(&cb[(size_t)(kt * 64 + k) * C_DIM + c0g + c4]);
            }
            __syncthreads();

#pragma unroll
            for (int c0 = 0; c0 < 64; c0 += 4) {
                float4 xv[4], bv[4];
#pragma unroll
                for (int s = 0; s < 4; ++s)
                    xv[s] = *reinterpret_cast<const float4*>(&Xs[c0 + s][4 * ty]);
#pragma unroll
                for (int j = 0; j < 4; ++j)
                    bv[j] = *reinterpret_cast<const float4*>(&Bs[16 * j + tx][c0]);
#pragma unroll
                for (int i = 0; i < 4; ++i) {
#pragma unroll
                    for (int j = 0; j < 4; ++j) {
                        float xi0 = (i == 0) ? xv[0].x : (i == 1) ? xv[0].y : (i == 2) ? xv[0].z : xv[0].w;
                        float xi1 = (i == 0) ? xv[1].x : (i == 1) ? xv[1].y : (i == 2) ? xv[1].z : xv[1].w;
                        float xi2 = (i == 0) ? xv[2].x : (i == 1) ? xv[2].y : (i == 2) ? xv[2].z : xv[2].w;
                        float xi3 = (i == 0) ? xv[3].x : (i == 1) ? xv[3].y : (i == 2) ? xv[3].z : xv[3].w;
                        acc[i][j] = fmaf(xi0, bv[j].x,
                                    fmaf(xi1, bv[j].y,
                                    fmaf(xi2, bv[j].z,
                                    fmaf(xi3, bv[j].w, acc[i][j]))));
                    }
                }
            }
        }

#pragma unroll
        for (int j = 0; j < 4; ++j) {
            int kg = kt * 64 + 16 * j + tx;
            float cnv = cns[kg];
#pragma unroll
            for (int i = 0; i < 4; ++i) {
                float d = cnv - 2.f * acc[i][j];
                if (d < best[i]) { best[i] = d; bidx[i] = kg; }
            }
        }
    }

#pragma unroll
    for (int i = 0; i < 4; ++i) {
#pragma unroll
        for (int off = 8; off >= 1; off >>= 1) {
            float od = __shfl_xor(best[i], off, 16);
            int   oi = __shfl_xor(bidx[i], off, 16);
            if (od < best[i] || (od == best[i] && oi < bidx[i])) { best[i] = od; bidx[i] = oi; }
        }
        if (tx == 0) idxs[4 * ty + i] = bidx[i];
    }
    __syncthreads();

    const int px = t & 63;
    const int c0 = t >> 6;
    const int code = idxs[px];
    const float* crow = cb + (size_t)code * C_DIM;
    const size_t obase = (size_t)b * (C_DIM * HW) + hw0 + px;
#pragma unroll 4
    for (int c = c0; c < C_DIM; c += 4) {
        float v = crow[c];
        out[obase + (size_t)c * HW] = v;
        out[obase + (size_t)c * HW + OUT_OFF] = v;
    }
}

extern "C" void kernel_launch(void* const* d_in, const int* in_sizes, int n_in,
                              void* d_out, int out_size, void* d_ws, size_t ws_size,
                              hipStream_t stream) {
    const float* z  = (const float*)d_in[0];
    const float* cb = (const float*)d_in[1];
    float* out = (float*)d_out;

    float* cnorm  = (float*)((char*)d_ws + WS_CNORM);
    int*   cnts   = (int*)((char*)d_ws + WS_CNTS);
    int*   list   = (int*)((char*)d_ws + WS_LIST);
    int*   idxarr = (int*)((char*)d_ws + WS_IDX);
    short* cb16   = (short*)((char*)d_ws + WS_CB16);

    vq_cnorm_kernel<<<K_CODES / 256, 256, 0, stream>>>(cb, cnorm);

    if (ws_size >= WS_NEED) {
        vq_cvt_kernel<<<128, 256, 0, stream>>>(cb, cb16);
        hipMemsetAsync(cnts, 0, 16, stream);
        vq_mfma_kernel<<<1024, 256, 0, stream>>>(z, cb16, cnorm, cnts, list, idxarr);
        vq_pair_kernel<<<512, 256, 0, stream>>>(z, cb, cnorm, cnts, list, idxarr);
        vq_rescan_kernel<<<1024, 256, 0, stream>>>(z, cb, cnorm, cnts, list, idxarr);
        vq_gather_kernel<<<1024, 256, 0, stream>>>(cb, idxarr, out);
    } else {
        vq_main_kernel<<<1024, 256, 0, stream>>>(z, cb, cnorm, out);
    }
}

// Round 4
// 251.139 us; speedup vs baseline: 14.2181x; 2.5304x over previous
//
#include <hip/hip_runtime.h>
#include <hip/hip_bf16.h>
#include <hip/hip_fp16.h>

// VQEmbedding straight-through forward, fp16-MFMA + top-3 margin + exact-refine.
//   z_e_x: [B=64, C=256, H=32, W=32] fp32, codebook: [K=1024, C=256] fp32
//   out: (z_q_x, z_q_x) both [B,C,H,W] fp32, concatenated flat.
//
// argmin_k ||x-c_k||^2 == argmin_k (||c_k||^2 - 2 x.c_k).
// fp16 (11-bit mantissa) distance error: sigma ~0.013, EPS=0.15 ~ 11 sigma.
//   gap13 < EPS -> full fp32 rescan, wave-block per pixel   (~300 px)
//   gap12 < EPS -> fp32 pair-compare, wave per pixel        (~6k px)
//   else        -> fp16 winner exact with overwhelming probability.

#define C_DIM 256
#define HW    1024
#define K_CODES 1024
#define OUT_OFF 16777216   // 64*256*32*32
#define EPS 0.15f

typedef _Float16 f16;
typedef _Float16 f16x8 __attribute__((ext_vector_type(8)));
typedef _Float16 f16x4 __attribute__((ext_vector_type(4)));
typedef float    f32x4 __attribute__((ext_vector_type(4)));

// ws layout (bytes, 16B aligned):
//   cnorm  f32[1024]       0        4096
//   cnts   int[4]          4096     16     ([0]=pairs, [1]=rescans)
//   list   int[65536]      4112     262144 (pairs grow from 0, rescans from top)
//   idxarr int[65536]      266256   262144
//   cb16   f16[1024*256]   528400   524288
#define WS_CNORM 0
#define WS_CNTS  4096
#define WS_LIST  4112
#define WS_IDX   266256
#define WS_CB16  528400
#define WS_NEED  1052688u

// prep: one wave per codebook row -> fp32 cnorm + fp16 codebook copy
__global__ __launch_bounds__(256) void vq_prep_kernel(const float* __restrict__ cb,
                                                      float* __restrict__ cnorm,
                                                      f16* __restrict__ cb16) {
    const int lane = threadIdx.x & 63;
    const int k    = blockIdx.x * 4 + (threadIdx.x >> 6);
    float4 v = *reinterpret_cast<const float4*>(&cb[(size_t)k * C_DIM + 4 * lane]);
    f16x4 h = { (f16)v.x, (f16)v.y, (f16)v.z, (f16)v.w };
    *reinterpret_cast<f16x4*>(&cb16[(size_t)k * C_DIM + 4 * lane]) = h;
    float s = v.x * v.x + v.y * v.y + v.z * v.z + v.w * v.w;
#pragma unroll
    for (int m = 1; m < 64; m <<= 1) s += __shfl_xor(s, m, 64);
    if (lane == 0) cnorm[k] = s;
}

// Main MFMA kernel: block = 64 px x all 1024 codes in 16 tiles of 64.
// 4 waves in 2x2 (px-half x code-half) quadrants; K-loop 8 steps of 32 over d.
// Tracks per-pixel top-3 distances (+ top-2 indices).
__global__ __launch_bounds__(256, 2) void vq_mfma_kernel(const float* __restrict__ z,
                                                         const f16* __restrict__ cb16,
                                                         const float* __restrict__ cnorm,
                                                         int* __restrict__ cnts,
                                                         int* __restrict__ list,
                                                         int* __restrict__ idxarr) {
    // 264 = 256 + 8 pad: row stride 528 B -> fragment reads are 2-way (free).
    __shared__ __align__(16) f16 Xs[64][264];
    __shared__ __align__(16) f16 Cs[64][264];
    __shared__ float cns[K_CODES];
    __shared__ float sb1[2][64], sb2[2][64], sb3[2][64];
    __shared__ int   si1[2][64], si2[2][64];

    const int t   = threadIdx.x;
    const int b   = blockIdx.x >> 4;
    const int hw0 = (blockIdx.x & 15) << 6;
    const size_t zbase = (size_t)b * (C_DIM * HW) + hw0;

    // stage X: fp32 global (coalesced float4 over px) -> fp16 LDS [px][d]
#pragma unroll
    for (int r = 0; r < 16; ++r) {
        int id  = t + 256 * r;
        int c   = id >> 4;
        int px4 = (id & 15) << 2;
        float4 v = *reinterpret_cast<const float4*>(&z[zbase + (size_t)c * HW + px4]);
        Xs[px4 + 0][c] = (f16)v.x;
        Xs[px4 + 1][c] = (f16)v.y;
        Xs[px4 + 2][c] = (f16)v.z;
        Xs[px4 + 3][c] = (f16)v.w;
    }
#pragma unroll
    for (int r = 0; r < 4; ++r) cns[t + 256 * r] = cnorm[t + 256 * r];

    const int lane = t & 63;
    const int w    = t >> 6;
    const int wm   = w >> 1;      // px half
    const int wn   = w & 1;       // code half
    const int l15  = lane & 15;
    const int l4   = lane >> 4;

    float b1[8], b2[8], b3[8]; int i1[8], i2[8];
#pragma unroll
    for (int s = 0; s < 8; ++s) {
        b1[s] = 3.4e38f; b2[s] = 3.4e38f; b3[s] = 3.4e38f; i1[s] = 0; i2[s] = 0;
    }

    const int arow0 = 32 * wm + l15;
    const int brow0 = 32 * wn + l15;

    for (int kt = 0; kt < 16; ++kt) {
        __syncthreads();
        const f16* csrc = cb16 + (size_t)(kt * 64) * C_DIM;
#pragma unroll
        for (int r = 0; r < 8; ++r) {
            int id   = t + 256 * r;
            int code = id >> 5;
            int dp   = (id & 31) << 3;
            *reinterpret_cast<f16x8*>(&Cs[code][dp]) =
                *reinterpret_cast<const f16x8*>(&csrc[code * C_DIM + dp]);
        }
        __syncthreads();

        f32x4 acc00 = 0.f, acc01 = 0.f, acc10 = 0.f, acc11 = 0.f;
#pragma unroll
        for (int ks = 0; ks < 8; ++ks) {
            int dsl = ks * 32 + l4 * 8;
            f16x8 a0 = *reinterpret_cast<const f16x8*>(&Xs[arow0][dsl]);
            f16x8 a1 = *reinterpret_cast<const f16x8*>(&Xs[arow0 + 16][dsl]);
            f16x8 c0 = *reinterpret_cast<const f16x8*>(&Cs[brow0][dsl]);
            f16x8 c1 = *reinterpret_cast<const f16x8*>(&Cs[brow0 + 16][dsl]);
            acc00 = __builtin_amdgcn_mfma_f32_16x16x32_f16(a0, c0, acc00, 0, 0, 0);
            acc01 = __builtin_amdgcn_mfma_f32_16x16x32_f16(a0, c1, acc01, 0, 0, 0);
            acc10 = __builtin_amdgcn_mfma_f32_16x16x32_f16(a1, c0, acc10, 0, 0, 0);
            acc11 = __builtin_amdgcn_mfma_f32_16x16x32_f16(a1, c1, acc11, 0, 0, 0);
        }

        // dist = ||c||^2 - 2 x.c ; D layout: row(px)=(l>>4)*4+reg, col(code)=l&15
#pragma unroll
        for (int mi = 0; mi < 2; ++mi) {
#pragma unroll
            for (int nj = 0; nj < 2; ++nj) {
                int code = kt * 64 + 32 * wn + 16 * nj + l15;
                float cnv = cns[code];
                f32x4 a = (mi == 0) ? ((nj == 0) ? acc00 : acc01)
                                    : ((nj == 0) ? acc10 : acc11);
#pragma unroll
                for (int reg = 0; reg < 4; ++reg) {
                    float d = fmaf(-2.f, a[reg], cnv);
                    int s = mi * 4 + reg;
                    bool lt1 = d < b1[s];
                    bool lt2 = d < b2[s];
                    bool lt3 = d < b3[s];
                    b3[s] = lt2 ? b2[s] : (lt3 ? d : b3[s]);
                    i2[s] = lt1 ? i1[s] : (lt2 ? code : i2[s]);
                    b2[s] = lt1 ? b1[s] : (lt2 ? d : b2[s]);
                    i1[s] = lt1 ? code : i1[s];
                    b1[s] = lt1 ? d : b1[s];
                }
            }
        }
    }

    // reduce top-3 across the 16 code-lanes (same l4 group), lowest-idx ties
#pragma unroll
    for (int s = 0; s < 8; ++s) {
        float v1 = b1[s], v2 = b2[s], v3 = b3[s]; int j1 = i1[s], j2 = i2[s];
#pragma unroll
        for (int m = 1; m < 16; m <<= 1) {
            float o1 = __shfl_xor(v1, m, 16);
            float o2 = __shfl_xor(v2, m, 16);
            float o3 = __shfl_xor(v3, m, 16);
            int  oj1 = __shfl_xor(j1, m, 16);
            int  oj2 = __shfl_xor(j2, m, 16);
            bool sw = (o1 < v1) || (o1 == v1 && oj1 < j1);
            float A1 = sw ? o1 : v1, A2 = sw ? o2 : v2, A3 = sw ? o3 : v3;
            int  Aj1 = sw ? oj1 : j1, Aj2 = sw ? oj2 : j2;
            float B1 = sw ? v1 : o1, B2 = sw ? v2 : o2;
            float B3 = sw ? v3 : o3;
            int  Bj1 = sw ? j1 : oj1;
            bool t2B = (B1 < A2) || (B1 == A2 && Bj1 < Aj2);
            v1 = A1; j1 = Aj1;
            v2 = t2B ? B1 : A2; j2 = t2B ? Bj1 : Aj2;
            v3 = t2B ? fminf(A2, B2) : fminf(A3, B1);
        }
        if (l15 == 0) {
            int mi = s >> 2, reg = s & 3;
            int px = 32 * wm + 16 * mi + l4 * 4 + reg;
            sb1[wn][px] = v1; sb2[wn][px] = v2; sb3[wn][px] = v3;
            si1[wn][px] = j1; si2[wn][px] = j2;
        }
    }
    __syncthreads();

    // combine the two code-halves, write idx, classify margin
    if (t < 64) {
        float a1v = sb1[0][t], a2v = sb2[0][t], a3v = sb3[0][t];
        int   aj1 = si1[0][t], aj2 = si2[0][t];
        float c1v = sb1[1][t], c2v = sb2[1][t], c3v = sb3[1][t];
        int   cj1 = si1[1][t], cj2 = si2[1][t];
        bool sw = (c1v < a1v) || (c1v == a1v && cj1 < aj1);
        float A1 = sw ? c1v : a1v, A2 = sw ? c2v : a2v, A3 = sw ? c3v : a3v;
        int  Aj1 = sw ? cj1 : aj1, Aj2 = sw ? cj2 : aj2;
        float B1 = sw ? a1v : c1v, B2 = sw ? a2v : c2v;
        float B3 = sw ? a3v : c3v;
        int  Bj1 = sw ? aj1 : cj1;
        bool t2B = (B1 < A2) || (B1 == A2 && Bj1 < Aj2);
        float v1 = A1;            int j1 = Aj1;
        float v2 = t2B ? B1 : A2; int j2 = t2B ? Bj1 : Aj2;
        float v3 = t2B ? fminf(A2, B2) : fminf(A3, B1);

        int gp = blockIdx.x * 64 + t;
        idxarr[gp] = j1;
        if (v3 - v1 < EPS) {            // >=3 candidates: full rescan (rare)
            int p = atomicAdd(&cnts[1], 1);
            list[65535 - p] = gp;
        } else if (v2 - v1 < EPS) {     // exactly 2 candidates: pair compare
            int p = atomicAdd(&cnts[0], 1);
            list[p] = gp | (j2 << 16);
        }
    }
}

// Exact fp32 compare of the two candidate codes; one wave per pixel.
__global__ __launch_bounds__(256) void vq_pair_kernel(const float* __restrict__ z,
                                                      const float* __restrict__ cb,
                                                      const float* __restrict__ cnorm,
                                                      const int* __restrict__ cnts,
                                                      const int* __restrict__ list,
                                                      int* __restrict__ idxarr) {
    const int lane = threadIdx.x & 63;
    const int wid  = (blockIdx.x * 256 + threadIdx.x) >> 6;
    const int nw   = gridDim.x * 4;
    const int np   = cnts[0];
    for (int p = wid; p < np; p += nw) {
        int e  = list[p];
        int px = e & 0xFFFF;
        int k2 = (e >> 16) & 0x3FF;
        int k1 = idxarr[px];
        int b = px >> 10, hw = px & 1023;
        const float* xb = z + (size_t)b * (C_DIM * HW) + hw;
        float x0 = xb[(size_t)(4 * lane + 0) * HW];
        float x1 = xb[(size_t)(4 * lane + 1) * HW];
        float x2 = xb[(size_t)(4 * lane + 2) * HW];
        float x3 = xb[(size_t)(4 * lane + 3) * HW];
        float4 a1 = *reinterpret_cast<const float4*>(&cb[(size_t)k1 * C_DIM + 4 * lane]);
        float4 a2 = *reinterpret_cast<const float4*>(&cb[(size_t)k2 * C_DIM + 4 * lane]);
        float s1 = fmaf(x0, a1.x, fmaf(x1, a1.y, fmaf(x2, a1.z, x3 * a1.w)));
        float s2 = fmaf(x0, a2.x, fmaf(x1, a2.y, fmaf(x2, a2.z, x3 * a2.w)));
#pragma unroll
        for (int m = 1; m < 64; m <<= 1) {
            s1 += __shfl_xor(s1, m, 64);
            s2 += __shfl_xor(s2, m, 64);
        }
        if (lane == 0) {
            float d1 = fmaf(-2.f, s1, cnorm[k1]);
            float d2 = fmaf(-2.f, s2, cnorm[k2]);
            if (d2 < d1 || (d2 == d1 && k2 < k1)) idxarr[px] = k2;
        }
    }
}

// Exact fp32 re-argmin over all 1024 codes; one 64-thread wave-block per pixel.
// Each lane owns 16 codes (k = r*64 + lane), streams rows as float4 from L2.
__global__ __launch_bounds__(64) void vq_rescan_kernel(const float* __restrict__ z,
                                                       const float* __restrict__ cb,
                                                       const float* __restrict__ cnorm,
                                                       const int* __restrict__ cnts,
                                                       const int* __restrict__ list,
                                                       int* __restrict__ idxarr) {
    __shared__ float xw[C_DIM];
    const int lane = threadIdx.x;
    const int nr = cnts[1];
    for (int q = blockIdx.x; q < nr; q += gridDim.x) {
        int gp = list[65535 - q];
        int b = gp >> 10, hw = gp & 1023;
        const float* xb = z + (size_t)b * (C_DIM * HW) + hw;
        __syncthreads();   // previous iteration's readers done
#pragma unroll
        for (int j = 0; j < 4; ++j)
            xw[4 * lane + j] = xb[(size_t)(4 * lane + j) * HW];
        __syncthreads();
        float bd = 3.4e38f; int bi = 0;
#pragma unroll
        for (int r = 0; r < 16; ++r) {
            int k = r * 64 + lane;   // ascending per lane -> strict < keeps lowest
            const float4* cr = reinterpret_cast<const float4*>(cb + (size_t)k * C_DIM);
            float s0 = 0.f, s1 = 0.f, s2 = 0.f, s3 = 0.f;
#pragma unroll 4
            for (int d4 = 0; d4 < 64; ++d4) {
                float4 cv = cr[d4];
                s0 = fmaf(xw[4 * d4 + 0], cv.x, s0);
                s1 = fmaf(xw[4 * d4 + 1], cv.y, s1);
                s2 = fmaf(xw[4 * d4 + 2], cv.z, s2);
                s3 = fmaf(xw[4 * d4 + 3], cv.w, s3);
            }
            float dist = fmaf(-2.f, (s0 + s1) + (s2 + s3), cnorm[k]);
            if (dist < bd) { bd = dist; bi = k; }
        }
#pragma unroll
        for (int m = 1; m < 64; m <<= 1) {
            float od = __shfl_xor(bd, m, 64);
            int   oi = __shfl_xor(bi, m, 64);
            if (od < bd || (od == bd && oi < bi)) { bd = od; bi = oi; }
        }
        if (lane == 0) idxarr[gp] = bi;
    }
}

// Gather final codes, write both outputs as float4 (1 KB per wave-instr).
// Block = 256 contiguous pixels of one image; thread -> 4 adjacent px.
__global__ __launch_bounds__(256) void vq_gather_kernel(const float* __restrict__ cb,
                                                        const int* __restrict__ idxarr,
                                                        float* __restrict__ out) {
    __shared__ int idxs[256];
    const int t = threadIdx.x;
    idxs[t] = idxarr[blockIdx.x * 256 + t];
    __syncthreads();
    const int b     = blockIdx.x >> 2;
    const int hw0   = (blockIdx.x & 3) << 8;
    const int px4   = (t & 63) << 2;
    const int cbase = t >> 6;
    const float* r0 = cb + (size_t)idxs[px4 + 0] * C_DIM;
    const float* r1 = cb + (size_t)idxs[px4 + 1] * C_DIM;
    const float* r2 = cb + (size_t)idxs[px4 + 2] * C_DIM;
    const float* r3 = cb + (size_t)idxs[px4 + 3] * C_DIM;
    const size_t obase = (size_t)b * (C_DIM * HW) + hw0 + px4;
#pragma unroll 8
    for (int c = cbase; c < C_DIM; c += 4) {
        float4 v = { r0[c], r1[c], r2[c], r3[c] };
        *reinterpret_cast<float4*>(&out[obase + (size_t)c * HW]) = v;
        *reinterpret_cast<float4*>(&out[obase + (size_t)c * HW + OUT_OFF]) = v;
    }
}

// ---------------- fallback (round-1 exact fp32 kernel, needs only 4KB ws) ----
__global__ __launch_bounds__(256) void vq_cnorm_kernel(const float* __restrict__ cb,
                                                       float* __restrict__ cnorm) {
    int k = blockIdx.x * 256 + threadIdx.x;
    if (k >= K_CODES) return;
    const float4* row = reinterpret_cast<const float4*>(cb + (size_t)k * C_DIM);
    float s = 0.f;
#pragma unroll 8
    for (int u = 0; u < C_DIM / 4; ++u) {
        float4 v = row[u];
        s += v.x * v.x + v.y * v.y + v.z * v.z + v.w * v.w;
    }
    cnorm[k] = s;
}

__global__ __launch_bounds__(256, 4) void vq_main_kernel(const float* __restrict__ z,
                                                         const float* __restrict__ cb,
                                                         const float* __restrict__ cnorm,
                                                         float* __restrict__ out) {
    __shared__ float Xs[64][64];
    __shared__ float Bs[64][68];
    __shared__ float cns[K_CODES];
    __shared__ int   idxs[64];

    const int t  = threadIdx.x;
    const int tx = t & 15;
    const int ty = t >> 4;
    const int b   = blockIdx.x >> 4;
    const int hw0 = (blockIdx.x & 15) << 6;
    const size_t zbase = (size_t)b * (C_DIM * HW) + hw0;

#pragma unroll
    for (int r = 0; r < 4; ++r) cns[t + 256 * r] = cnorm[t + 256 * r];

    float best[4];
    int   bidx[4];
#pragma unroll
    for (int i = 0; i < 4; ++i) { best[i] = 3.4e38f; bidx[i] = 0; }

    for (int kt = 0; kt < 16; ++kt) {
        float acc[4][4];
#pragma unroll
        for (int i = 0; i < 4; ++i)
#pragma unroll
            for (int j = 0; j < 4; ++j) acc[i][j] = 0.f;

        for (int cc = 0; cc < 4; ++cc) {
            const int c0g = cc * 64;
            __syncthreads();
#pragma unroll
            for (int r = 0; r < 4; ++r) {
                int c   = (t >> 4) + 16 * r;
                int px4 = (t & 15) * 4;
                *reinterpret_cast<float4*>(&Xs[c][px4]) =
                    *reinterpret_cast<const float4*>(&z[zbase + (size_t)(c0g + c) * HW + px4]);
                int k  = (t >> 4) + 16 * r;
                int c4 = (t & 15) * 4;
                *reinterpret_cast<float4*>(&Bs[k][c4]) =
                    *reinterpret_cast<const float4*>(&cb[(size_t)(kt * 64 + k) * C_DIM + c0g + c4]);
            }
            __syncthreads();

#pragma unroll
            for (int c0 = 0; c0 < 64; c0 += 4) {
                float4 xv[4], bv[4];
#pragma unroll
                for (int s = 0; s < 4; ++s)
                    xv[s] = *reinterpret_cast<const float4*>(&Xs[c0 + s][4 * ty]);
#pragma unroll
                for (int j = 0; j < 4; ++j)
                    bv[j] = *reinterpret_cast<const float4*>(&Bs[16 * j + tx][c0]);
#pragma unroll
                for (int i = 0; i < 4; ++i) {
#pragma unroll
                    for (int j = 0; j < 4; ++j) {
                        float xi0 = (i == 0) ? xv[0].x : (i == 1) ? xv[0].y : (i == 2) ? xv[0].z : xv[0].w;
                        float xi1 = (i == 0) ? xv[1].x : (i == 1) ? xv[1].y : (i == 2) ? xv[1].z : xv[1].w;
                        float xi2 = (i == 0) ? xv[2].x : (i == 1) ? xv[2].y : (i == 2) ? xv[2].z : xv[2].w;
                        float xi3 = (i == 0) ? xv[3].x : (i == 1) ? xv[3].y : (i == 2) ? xv[3].z : xv[3].w;
                        acc[i][j] = fmaf(xi0, bv[j].x,
                                    fmaf(xi1, bv[j].y,
                                    fmaf(xi2, bv[j].z,
                                    fmaf(xi3, bv[j].w, acc[i][j]))));
                    }
                }
            }
        }

#pragma unroll
        for (int j = 0; j < 4; ++j) {
            int kg = kt * 64 + 16 * j + tx;
            float cnv = cns[kg];
#pragma unroll
            for (int i = 0; i < 4; ++i) {
                float d = cnv - 2.f * acc[i][j];
                if (d < best[i]) { best[i] = d; bidx[i] = kg; }
            }
        }
    }

#pragma unroll
    for (int i = 0; i < 4; ++i) {
#pragma unroll
        for (int off = 8; off >= 1; off >>= 1) {
            float od = __shfl_xor(best[i], off, 16);
            int   oi = __shfl_xor(bidx[i], off, 16);
            if (od < best[i] || (od == best[i] && oi < bidx[i])) { best[i] = od; bidx[i] = oi; }
        }
        if (tx == 0) idxs[4 * ty + i] = bidx[i];
    }
    __syncthreads();

    const int px = t & 63;
    const int c0 = t >> 6;
    const int code = idxs[px];
    const float* crow = cb + (size_t)code * C_DIM;
    const size_t obase = (size_t)b * (C_DIM * HW) + hw0 + px;
#pragma unroll 4
    for (int c = c0; c < C_DIM; c += 4) {
        float v = crow[c];
        out[obase + (size_t)c * HW] = v;
        out[obase + (size_t)c * HW + OUT_OFF] = v;
    }
}

extern "C" void kernel_launch(void* const* d_in, const int* in_sizes, int n_in,
                              void* d_out, int out_size, void* d_ws, size_t ws_size,
                              hipStream_t stream) {
    const float* z  = (const float*)d_in[0];
    const float* cb = (const float*)d_in[1];
    float* out = (float*)d_out;

    float* cnorm  = (float*)((char*)d_ws + WS_CNORM);
    int*   cnts   = (int*)((char*)d_ws + WS_CNTS);
    int*   list   = (int*)((char*)d_ws + WS_LIST);
    int*   idxarr = (int*)((char*)d_ws + WS_IDX);
    f16*   cb16   = (f16*)((char*)d_ws + WS_CB16);

    if (ws_size >= WS_NEED) {
        vq_prep_kernel<<<K_CODES / 4, 256, 0, stream>>>(cb, cnorm, cb16);
        hipMemsetAsync(cnts, 0, 16, stream);
        vq_mfma_kernel<<<1024, 256, 0, stream>>>(z, cb16, cnorm, cnts, list, idxarr);
        vq_pair_kernel<<<512, 256, 0, stream>>>(z, cb, cnorm, cnts, list, idxarr);
        vq_rescan_kernel<<<2048, 64, 0, stream>>>(z, cb, cnorm, cnts, list, idxarr);
        vq_gather_kernel<<<256, 256, 0, stream>>>(cb, idxarr, out);
    } else {
        vq_cnorm_kernel<<<K_CODES / 256, 256, 0, stream>>>(cb, cnorm);
        vq_main_kernel<<<1024, 256, 0, stream>>>(z, cb, cnorm, out);
    }
}

// Round 5
// 226.447 us; speedup vs baseline: 15.7684x; 1.1090x over previous
//
#include <hip/hip_runtime.h>
#include <hip/hip_fp16.h>

// VQEmbedding straight-through forward, fp16-MFMA (A-in-registers, fragment-
// ordered codebook, global_load_lds staging) + top-4 packed keys + exact refine.
//   z_e_x: [B=64, C=256, H=32, W=32] fp32, codebook: [K=1024, C=256] fp32
//   out: (z_q_x, z_q_x) both [B,C,H,W] fp32, concatenated flat.
//
// argmin_k ||x-c_k||^2 == argmin_k (||c_k||^2 + 256 - 2 x.c_k)  (uniform bias)
// Keys: fp32 distance bits rounded at 10 low bits, low 10 bits = code index.
// Distance range certified (312..714) => positive, quant err <= 0.031.
// fp16 input-rounding sigma ~0.013; EPS=0.22 => unflagged true gap >= 9 sigma.
//   gap14 < EPS -> full fp32 rescan   (~tens of px)
//   gap13 < EPS -> 3-candidate exact  (~hundreds)
//   gap12 < EPS -> 2-candidate exact  (~10k)

#define C_DIM 256
#define HW    1024
#define K_CODES 1024
#define OUT_OFF 16777216   // 64*256*32*32
#define EPS 0.22f

typedef _Float16 f16;
typedef _Float16 f16x8 __attribute__((ext_vector_type(8)));
typedef float    f32x4 __attribute__((ext_vector_type(4)));

// ws layout (bytes, 16B aligned) — identical footprint to round-4 (proven fit):
//   cnorm  f32[1024]       0        4096   (biased +256)
//   cnts   int[4]          4096     16     ([0]=pair+triple, [1]=rescan)
//   arena  int[65536]      4112     262144 (pairs/triples bottom-up, rescans top-down)
//   idxarr int[65536]      266256   262144 (triple px: bits 20-29 carry 3rd cand)
//   cb16f  f16[1024*256]   528400   524288 (MFMA-fragment order)
#define WS_CNORM 0
#define WS_CNTS  4096
#define WS_ARENA 4112
#define WS_IDX   266256
#define WS_CB16  528400
#define WS_NEED  1052688u

__device__ __forceinline__ unsigned umn(unsigned a, unsigned b) { return a < b ? a : b; }
__device__ __forceinline__ unsigned umx(unsigned a, unsigned b) { return a > b ? a : b; }

// sorted-insert x into ascending quad (a1..a4)
__device__ __forceinline__ void ins4(unsigned& a1, unsigned& a2, unsigned& a3,
                                     unsigned& a4, unsigned x) {
    unsigned u1 = umx(a1, x);  a1 = umn(a1, x);
    unsigned u2 = umx(a2, u1); a2 = umn(a2, u1);
    unsigned u3 = umx(a3, u2); a3 = umn(a3, u2);
    a4 = umn(a4, u3);
}

__device__ __forceinline__ void gl16(const void* g, void* l) {
    __builtin_amdgcn_global_load_lds(
        (const __attribute__((address_space(1))) unsigned int*)g,
        (__attribute__((address_space(3))) unsigned int*)l, 16, 0, 0);
}

// ---- prep 1: cnorm (+256 bias) and zero counters. wave per codebook row.
__global__ __launch_bounds__(256) void vq_prep_cnorm(const float* __restrict__ cb,
                                                     float* __restrict__ cnorm,
                                                     int* __restrict__ cnts) {
    if (blockIdx.x == 0 && threadIdx.x < 4) cnts[threadIdx.x] = 0;
    const int lane = threadIdx.x & 63;
    const int k    = blockIdx.x * 4 + (threadIdx.x >> 6);
    float4 v = *reinterpret_cast<const float4*>(&cb[(size_t)k * C_DIM + 4 * lane]);
    float s = v.x * v.x + v.y * v.y + v.z * v.z + v.w * v.w;
#pragma unroll
    for (int m = 1; m < 64; m <<= 1) s += __shfl_xor(s, m, 64);
    if (lane == 0) cnorm[k] = s + 256.f;
}

// ---- prep 2: codebook -> fp16 in MFMA-fragment order.
// slot s = ((kt*4 + ct)*8 + kk)*64 + l holds 8 f16:
//   element j: cb[kt*64 + ct*16 + (l&15)][kk*32 + (l>>4)*8 + j]
__global__ __launch_bounds__(256) void vq_prep_cbf(const float* __restrict__ cb,
                                                   f16* __restrict__ cb16f) {
    int s  = blockIdx.x * 256 + threadIdx.x;     // 0..32767
    int l  = s & 63;
    int kk = (s >> 6) & 7;
    int ct = (s >> 9) & 3;
    int kt = s >> 11;
    int code = kt * 64 + ct * 16 + (l & 15);
    int k0   = kk * 32 + (l >> 4) * 8;
    const float* row = cb + (size_t)code * C_DIM + k0;
    float4 a = *reinterpret_cast<const float4*>(row);
    float4 b = *reinterpret_cast<const float4*>(row + 4);
    f16x8 h;
    h[0] = (f16)a.x; h[1] = (f16)a.y; h[2] = (f16)a.z; h[3] = (f16)a.w;
    h[4] = (f16)b.x; h[5] = (f16)b.y; h[6] = (f16)b.z; h[7] = (f16)b.w;
    *reinterpret_cast<f16x8*>(&cb16f[(size_t)s * 8]) = h;
}

// ---- main kernel: block = 128 px (4 waves x 32 px disjoint) x 1024 codes.
// A (pixels) in registers; Cs staged per 64-code tile via global_load_lds.
__global__ __launch_bounds__(256, 2) void vq_mfma_kernel(const float* __restrict__ z,
                                                         const f16* __restrict__ cb16f,
                                                         const float* __restrict__ cnorm,
                                                         int* __restrict__ cnts,
                                                         int* __restrict__ arena,
                                                         int* __restrict__ idxarr) {
    __shared__ __align__(16) union {
        float xs[64 * 129];    // staging: 64 channels x 128 px (stride 129)
        f16   cs[16384];       // Cs tile: 64 codes x 256 d, fragment order
    } L;
    __shared__ float cns[K_CODES];

    const int t    = threadIdx.x;
    const int bid  = blockIdx.x;
    const int b    = bid >> 3;
    const int hw0  = (bid & 7) << 7;
    const size_t zbase = (size_t)b * (C_DIM * HW) + hw0;

    const int lane = t & 63;
    const int w    = t >> 6;
    const int l15  = lane & 15;
    const int l4   = lane >> 4;

#pragma unroll
    for (int r = 0; r < 4; ++r) cns[t + 256 * r] = cnorm[t + 256 * r];

    // ---- load A fragments: af[tile][kk], px = w*32 + tile*16 + l15,
    //      k = kk*32 + l4*8 + j  (4 chunks of 64 channels via LDS transpose)
    f16x8 af[2][8];
#pragma unroll
    for (int cc = 0; cc < 4; ++cc) {
        __syncthreads();
#pragma unroll
        for (int i = 0; i < 8; ++i) {
            int id  = t + 256 * i;          // 0..2047
            int c   = id >> 5;              // 0..63
            int px4 = (id & 31) << 2;       // 0..124
            float4 v = *reinterpret_cast<const float4*>(
                &z[zbase + (size_t)(cc * 64 + c) * HW + px4]);
            float* xr = &L.xs[c * 129 + px4];
            xr[0] = v.x; xr[1] = v.y; xr[2] = v.z; xr[3] = v.w;
        }
        __syncthreads();
#pragma unroll
        for (int kkl = 0; kkl < 2; ++kkl) {
#pragma unroll
            for (int tile = 0; tile < 2; ++tile) {
                int px    = w * 32 + tile * 16 + l15;
                int cbase = kkl * 32 + l4 * 8;
                f16x8 h;
#pragma unroll
                for (int j = 0; j < 8; ++j)
                    h[j] = (f16)L.xs[(cbase + j) * 129 + px];
                af[tile][cc * 2 + kkl] = h;
            }
        }
    }

    unsigned k1[8], k2[8], k3[8], k4[8];
#pragma unroll
    for (int s = 0; s < 8; ++s) { k1[s] = k2[s] = k3[s] = k4[s] = 0xFFFFFFFFu; }

    for (int kt = 0; kt < 16; ++kt) {
        __syncthreads();   // prior tile's readers done (covers prologue on kt=0)
        const f16* src = cb16f + (size_t)kt * 16384;
#pragma unroll
        for (int r = 0; r < 8; ++r) {
            int slot = r * 256 + t;
            gl16(src + (size_t)slot * 8, &L.cs[slot * 8]);
        }
        __syncthreads();   // compiler drains vmcnt before barrier -> Cs ready

        f32x4 acc[2][4];
#pragma unroll
        for (int i = 0; i < 2; ++i)
#pragma unroll
            for (int j = 0; j < 4; ++j) acc[i][j] = (f32x4)0.f;

#pragma unroll
        for (int kk = 0; kk < 8; ++kk) {
            f16x8 b0 = *reinterpret_cast<const f16x8*>(&L.cs[((0 * 8 + kk) * 64 + lane) * 8]);
            f16x8 b1 = *reinterpret_cast<const f16x8*>(&L.cs[((1 * 8 + kk) * 64 + lane) * 8]);
            f16x8 b2 = *reinterpret_cast<const f16x8*>(&L.cs[((2 * 8 + kk) * 64 + lane) * 8]);
            f16x8 b3 = *reinterpret_cast<const f16x8*>(&L.cs[((3 * 8 + kk) * 64 + lane) * 8]);
#pragma unroll
            for (int tile = 0; tile < 2; ++tile) {
                acc[tile][0] = __builtin_amdgcn_mfma_f32_16x16x32_f16(af[tile][kk], b0, acc[tile][0], 0, 0, 0);
                acc[tile][1] = __builtin_amdgcn_mfma_f32_16x16x32_f16(af[tile][kk], b1, acc[tile][1], 0, 0, 0);
                acc[tile][2] = __builtin_amdgcn_mfma_f32_16x16x32_f16(af[tile][kk], b2, acc[tile][2], 0, 0, 0);
                acc[tile][3] = __builtin_amdgcn_mfma_f32_16x16x32_f16(af[tile][kk], b3, acc[tile][3], 0, 0, 0);
            }
        }

        // keys: d = cnorm+256 - 2 x.c ; round low 10 bits, pack code index
        const int ktbase = kt * 64;
#pragma unroll
        for (int ct = 0; ct < 4; ++ct) {
            int code  = ktbase + ct * 16 + l15;
            float cnv = cns[code];
#pragma unroll
            for (int tile = 0; tile < 2; ++tile) {
#pragma unroll
                for (int reg = 0; reg < 4; ++reg) {
                    float d = fmaf(-2.f, acc[tile][ct][reg], cnv);
                    unsigned key = ((__float_as_uint(d) + 512u) & 0xFFFFFC00u) | (unsigned)code;
                    int s = tile * 4 + reg;
                    ins4(k1[s], k2[s], k3[s], k4[s], key);
                }
            }
        }
    }

    // ---- reduce top-4 across the 16 code-lanes (same l4 group); classify.
#pragma unroll
    for (int s = 0; s < 8; ++s) {
        unsigned a1 = k1[s], a2 = k2[s], a3 = k3[s], a4 = k4[s];
#pragma unroll
        for (int m = 1; m < 16; m <<= 1) {
            unsigned b1 = __shfl_xor(a1, m, 16);
            unsigned b2 = __shfl_xor(a2, m, 16);
            unsigned b3 = __shfl_xor(a3, m, 16);
            unsigned b4 = __shfl_xor(a4, m, 16);
            ins4(a1, a2, a3, a4, b1);
            ins4(a1, a2, a3, a4, b2);
            ins4(a1, a2, a3, a4, b3);
            ins4(a1, a2, a3, a4, b4);
        }
        if (l15 == 0) {
            int px = (w << 5) + ((s >> 2) << 4) + (l4 << 2) + (s & 3);
            int gp = (bid << 7) + px;
            float v1 = __uint_as_float(a1 & 0xFFFFFC00u);
            float v2 = __uint_as_float(a2 & 0xFFFFFC00u);
            float v3 = __uint_as_float(a3 & 0xFFFFFC00u);
            float v4 = __uint_as_float(a4 & 0xFFFFFC00u);
            int i1 = (int)(a1 & 1023u);
            int i2 = (int)(a2 & 1023u);
            int i3 = (int)(a3 & 1023u);
            int iv = i1;
            if (v4 - v1 < EPS) {                 // >=4 candidates: full rescan
                int p = atomicAdd(&cnts[1], 1);
                arena[65535 - p] = gp;
            } else if (v3 - v1 < EPS) {          // 3 candidates
                int p = atomicAdd(&cnts[0], 1);
                arena[p] = gp | (i2 << 16) | (int)0x80000000u;
                iv = i1 | (i3 << 20);
            } else if (v2 - v1 < EPS) {          // 2 candidates
                int p = atomicAdd(&cnts[0], 1);
                arena[p] = gp | (i2 << 16);
            }
            idxarr[gp] = iv;
        }
    }
}

// ---- refine: exact fp32 compare of 2 or 3 candidates; one wave per entry.
__global__ __launch_bounds__(256) void vq_refine_kernel(const float* __restrict__ z,
                                                        const float* __restrict__ cb,
                                                        const float* __restrict__ cnorm,
                                                        const int* __restrict__ cnts,
                                                        const int* __restrict__ arena,
                                                        int* __restrict__ idxarr) {
    const int lane = threadIdx.x & 63;
    const int wid  = (blockIdx.x * 256 + threadIdx.x) >> 6;
    const int nw   = gridDim.x * 4;
    const int nb   = cnts[0];
    for (int i = wid; i < nb; i += nw) {
        int e  = arena[i];
        int gp = e & 0xFFFF;
        int j2 = (e >> 16) & 1023;
        bool tri = e < 0;
        int iv = idxarr[gp];
        int c1 = iv & 1023;
        int j3 = (iv >> 20) & 1023;
        int b = gp >> 10, hw = gp & 1023;
        const float* xb = z + (size_t)b * (C_DIM * HW) + hw;
        float x0 = xb[(size_t)(4 * lane + 0) * HW];
        float x1 = xb[(size_t)(4 * lane + 1) * HW];
        float x2 = xb[(size_t)(4 * lane + 2) * HW];
        float x3 = xb[(size_t)(4 * lane + 3) * HW];
        float4 r1 = *reinterpret_cast<const float4*>(&cb[(size_t)c1 * C_DIM + 4 * lane]);
        float4 r2 = *reinterpret_cast<const float4*>(&cb[(size_t)j2 * C_DIM + 4 * lane]);
        float s1 = fmaf(x0, r1.x, fmaf(x1, r1.y, fmaf(x2, r1.z, x3 * r1.w)));
        float s2 = fmaf(x0, r2.x, fmaf(x1, r2.y, fmaf(x2, r2.z, x3 * r2.w)));
        float s3 = 0.f;
        if (tri) {
            float4 r3 = *reinterpret_cast<const float4*>(&cb[(size_t)j3 * C_DIM + 4 * lane]);
            s3 = fmaf(x0, r3.x, fmaf(x1, r3.y, fmaf(x2, r3.z, x3 * r3.w)));
        }
#pragma unroll
        for (int m = 1; m < 64; m <<= 1) {
            s1 += __shfl_xor(s1, m, 64);
            s2 += __shfl_xor(s2, m, 64);
            s3 += __shfl_xor(s3, m, 64);
        }
        if (lane == 0) {
            float d1 = fmaf(-2.f, s1, cnorm[c1]);
            float d2 = fmaf(-2.f, s2, cnorm[j2]);
            int bi = c1; float bd = d1;
            if (d2 < bd || (d2 == bd && j2 < bi)) { bd = d2; bi = j2; }
            if (tri) {
                float d3 = fmaf(-2.f, s3, cnorm[j3]);
                if (d3 < bd || (d3 == bd && j3 < bi)) { bd = d3; bi = j3; }
            }
            idxarr[gp] = bi;
        }
    }
}

// ---- rescan: exact fp32 argmin over all 1024 codes; 64-thread block per px.
__global__ __launch_bounds__(64) void vq_rescan_kernel(const float* __restrict__ z,
                                                       const float* __restrict__ cb,
                                                       const float* __restrict__ cnorm,
                                                       const int* __restrict__ cnts,
                                                       const int* __restrict__ arena,
                                                       int* __restrict__ idxarr) {
    __shared__ float xw[C_DIM];
    const int lane = threadIdx.x;
    const int nr = cnts[1];
    for (int q = blockIdx.x; q < nr; q += gridDim.x) {
        int gp = arena[65535 - q];
        int b = gp >> 10, hw = gp & 1023;
        const float* xb = z + (size_t)b * (C_DIM * HW) + hw;
        __syncthreads();
#pragma unroll
        for (int j = 0; j < 4; ++j)
            xw[4 * lane + j] = xb[(size_t)(4 * lane + j) * HW];
        __syncthreads();
        float bd = 3.4e38f; int bi = 0;
#pragma unroll
        for (int r = 0; r < 16; ++r) {
            int k = r * 64 + lane;   // ascending per lane -> strict < keeps lowest
            const float4* cr = reinterpret_cast<const float4*>(cb + (size_t)k * C_DIM);
            float s0 = 0.f, s1 = 0.f, s2 = 0.f, s3 = 0.f;
#pragma unroll 4
            for (int d4 = 0; d4 < 64; ++d4) {
                float4 cv = cr[d4];
                s0 = fmaf(xw[4 * d4 + 0], cv.x, s0);
                s1 = fmaf(xw[4 * d4 + 1], cv.y, s1);
                s2 = fmaf(xw[4 * d4 + 2], cv.z, s2);
                s3 = fmaf(xw[4 * d4 + 3], cv.w, s3);
            }
            float dist = fmaf(-2.f, (s0 + s1) + (s2 + s3), cnorm[k]);
            if (dist < bd) { bd = dist; bi = k; }
        }
#pragma unroll
        for (int m = 1; m < 64; m <<= 1) {
            float od = __shfl_xor(bd, m, 64);
            int   oi = __shfl_xor(bi, m, 64);
            if (od < bd || (od == bd && oi < bi)) { bd = od; bi = oi; }
        }
        if (lane == 0) idxarr[gp] = bi;
    }
}

// ---- gather final codes, write both outputs as float4.
__global__ __launch_bounds__(256) void vq_gather_kernel(const float* __restrict__ cb,
                                                        const int* __restrict__ idxarr,
                                                        float* __restrict__ out) {
    __shared__ int idxs[256];
    const int t = threadIdx.x;
    idxs[t] = idxarr[blockIdx.x * 256 + t];
    __syncthreads();
    const int b     = blockIdx.x >> 2;
    const int hw0   = (blockIdx.x & 3) << 8;
    const int px4   = (t & 63) << 2;
    const int cbase = t >> 6;
    const float* r0 = cb + (size_t)idxs[px4 + 0] * C_DIM;
    const float* r1 = cb + (size_t)idxs[px4 + 1] * C_DIM;
    const float* r2 = cb + (size_t)idxs[px4 + 2] * C_DIM;
    const float* r3 = cb + (size_t)idxs[px4 + 3] * C_DIM;
    const size_t obase = (size_t)b * (C_DIM * HW) + hw0 + px4;
#pragma unroll 8
    for (int c = cbase; c < C_DIM; c += 4) {
        float4 v = { r0[c], r1[c], r2[c], r3[c] };
        *reinterpret_cast<float4*>(&out[obase + (size_t)c * HW]) = v;
        *reinterpret_cast<float4*>(&out[obase + (size_t)c * HW + OUT_OFF]) = v;
    }
}

// ---------------- fallback (round-1 exact fp32 kernels, needs only 4KB ws) ----
__global__ __launch_bounds__(256) void vq_cnorm_kernel(const float* __restrict__ cb,
                                                       float* __restrict__ cnorm) {
    int k = blockIdx.x * 256 + threadIdx.x;
    if (k >= K_CODES) return;
    const float4* row = reinterpret_cast<const float4*>(cb + (size_t)k * C_DIM);
    float s = 0.f;
#pragma unroll 8
    for (int u = 0; u < C_DIM / 4; ++u) {
        float4 v = row[u];
        s += v.x * v.x + v.y * v.y + v.z * v.z + v.w * v.w;
    }
    cnorm[k] = s;
}

__global__ __launch_bounds__(256, 4) void vq_main_kernel(const float* __restrict__ z,
                                                         const float* __restrict__ cb,
                                                         const float* __restrict__ cnorm,
                                                         float* __restrict__ out) {
    __shared__ float Xs[64][64];
    __shared__ float Bs[64][68];
    __shared__ float cns[K_CODES];
    __shared__ int   idxs[64];

    const int t  = threadIdx.x;
    const int tx = t & 15;
    const int ty = t >> 4;
    const int b   = blockIdx.x >> 4;
    const int hw0 = (blockIdx.x & 15) << 6;
    const size_t zbase = (size_t)b * (C_DIM * HW) + hw0;

#pragma unroll
    for (int r = 0; r < 4; ++r) cns[t + 256 * r] = cnorm[t + 256 * r];

    float best[4];
    int   bidx[4];
#pragma unroll
    for (int i = 0; i < 4; ++i) { best[i] = 3.4e38f; bidx[i] = 0; }

    for (int kt = 0; kt < 16; ++kt) {
        float acc[4][4];
#pragma unroll
        for (int i = 0; i < 4; ++i)
#pragma unroll
            for (int j = 0; j < 4; ++j) acc[i][j] = 0.f;

        for (int cc = 0; cc < 4; ++cc) {
            const int c0g = cc * 64;
            __syncthreads();
#pragma unroll
            for (int r = 0; r < 4; ++r) {
                int c   = (t >> 4) + 16 * r;
                int px4 = (t & 15) * 4;
                *reinterpret_cast<float4*>(&Xs[c][px4]) =
                    *reinterpret_cast<const float4*>(&z[zbase + (size_t)(c0g + c) * HW + px4]);
                int k  = (t >> 4) + 16 * r;
                int c4 = (t & 15) * 4;
                *reinterpret_cast<float4*>(&Bs[k][c4]) =
                    *reinterpret_cast<const float4*>(&cb[(size_t)(kt * 64 + k) * C_DIM + c0g + c4]);
            }
            __syncthreads();

#pragma unroll
            for (int c0 = 0; c0 < 64; c0 += 4) {
                float4 xv[4], bv[4];
#pragma unroll
                for (int s = 0; s < 4; ++s)
                    xv[s] = *reinterpret_cast<const float4*>(&Xs[c0 + s][4 * ty]);
#pragma unroll
                for (int j = 0; j < 4; ++j)
                    bv[j] = *reinterpret_cast<const float4*>(&Bs[16 * j + tx][c0]);
#pragma unroll
                for (int i = 0; i < 4; ++i) {
#pragma unroll
                    for (int j = 0; j < 4; ++j) {
                        float xi0 = (i == 0) ? xv[0].x : (i == 1) ? xv[0].y : (i == 2) ? xv[0].z : xv[0].w;
                        float xi1 = (i == 0) ? xv[1].x : (i == 1) ? xv[1].y : (i == 2) ? xv[1].z : xv[1].w;
                        float xi2 = (i == 0) ? xv[2].x : (i == 1) ? xv[2].y : (i == 2) ? xv[2].z : xv[2].w;
                        float xi3 = (i == 0) ? xv[3].x : (i == 1) ? xv[3].y : (i == 2) ? xv[3].z : xv[3].w;
                        acc[i][j] = fmaf(xi0, bv[j].x,
                                    fmaf(xi1, bv[j].y,
                                    fmaf(xi2, bv[j].z,
                                    fmaf(xi3, bv[j].w, acc[i][j]))));
                    }
                }
            }
        }

#pragma unroll
        for (int j = 0; j < 4; ++j) {
            int kg = kt * 64 + 16 * j + tx;
            float cnv = cns[kg];
#pragma unroll
            for (int i = 0; i < 4; ++i) {
                float d = cnv - 2.f * acc[i][j];
                if (d < best[i]) { best[i] = d; bidx[i] = kg; }
            }
        }
    }

#pragma unroll
    for (int i = 0; i < 4; ++i) {
#pragma unroll
        for (int off = 8; off >= 1; off >>= 1) {
            float od = __shfl_xor(best[i], off, 16);
            int   oi = __shfl_xor(bidx[i], off, 16);
            if (od < best[i] || (od == best[i] && oi < bidx[i])) { best[i] = od; bidx[i] = oi; }
        }
        if (tx == 0) idxs[4 * ty + i] = bidx[i];
    }
    __syncthreads();

    const int px = t & 63;
    const int c0 = t >> 6;
    const int code = idxs[px];
    const float* crow = cb + (size_t)code * C_DIM;
    const size_t obase = (size_t)b * (C_DIM * HW) + hw0 + px;
#pragma unroll 4
    for (int c = c0; c < C_DIM; c += 4) {
        float v = crow[c];
        out[obase + (size_t)c * HW] = v;
        out[obase + (size_t)c * HW + OUT_OFF] = v;
    }
}

extern "C" void kernel_launch(void* const* d_in, const int* in_sizes, int n_in,
                              void* d_out, int out_size, void* d_ws, size_t ws_size,
                              hipStream_t stream) {
    const float* z  = (const float*)d_in[0];
    const float* cb = (const float*)d_in[1];
    float* out = (float*)d_out;

    float* cnorm  = (float*)((char*)d_ws + WS_CNORM);
    int*   cnts   = (int*)((char*)d_ws + WS_CNTS);
    int*   arena  = (int*)((char*)d_ws + WS_ARENA);
    int*   idxarr = (int*)((char*)d_ws + WS_IDX);
    f16*   cb16f  = (f16*)((char*)d_ws + WS_CB16);

    if (ws_size >= WS_NEED) {
        vq_prep_cnorm<<<K_CODES / 4, 256, 0, stream>>>(cb, cnorm, cnts);
        vq_prep_cbf<<<128, 256, 0, stream>>>(cb, cb16f);
        vq_mfma_kernel<<<512, 256, 0, stream>>>(z, cb16f, cnorm, cnts, arena, idxarr);
        vq_refine_kernel<<<256, 256, 0, stream>>>(z, cb, cnorm, cnts, arena, idxarr);
        vq_rescan_kernel<<<128, 64, 0, stream>>>(z, cb, cnorm, cnts, arena, idxarr);
        vq_gather_kernel<<<256, 256, 0, stream>>>(cb, idxarr, out);
    } else {
        vq_cnorm_kernel<<<K_CODES / 256, 256, 0, stream>>>(cb, cnorm);
        vq_main_kernel<<<1024, 256, 0, stream>>>(z, cb, cnorm, out);
    }
}

// Round 6
// 175.761 us; speedup vs baseline: 20.3157x; 1.2884x over previous
//
#include <hip/hip_runtime.h>
#include <hip/hip_fp16.h>

// VQEmbedding straight-through forward, fp16-MFMA (A-in-registers, fragment-
// ordered codebook, double-buffered global_load_lds staging) + top-4 packed
// keys + exact refine.
//   z_e_x: [B=64, C=256, H=32, W=32] fp32, codebook: [K=1024, C=256] fp32
//   out: (z_q_x, z_q_x) both [B,C,H,W] fp32, concatenated flat.
//
// argmin_k ||x-c_k||^2 == argmin_k (||c_k||^2 + 256 - 2 x.c_k)  (uniform bias)
// Keys: fp32 distance bits truncated at 10 low bits | 10-bit code index.
// Distances certified positive (~[312,714]); truncation err <= 0.0625.
// fp16 input-rounding sigma ~0.013; EPS=0.22 - 0.0625 => true gap >= ~12 sigma.
//   gap14 < EPS -> full fp32 rescan   (rare)
//   gap13 < EPS -> 3-candidate exact  (rare)
//   gap12 < EPS -> 2-candidate exact  (~1-10k px)

#define C_DIM 256
#define HW    1024
#define K_CODES 1024
#define OUT_OFF 16777216   // 64*256*32*32
#define EPS 0.22f

typedef _Float16 f16;
typedef _Float16 f16x8 __attribute__((ext_vector_type(8)));
typedef float    f32x4 __attribute__((ext_vector_type(4)));

// ws layout (bytes, 16B aligned) — identical footprint to round-4/5 (proven):
//   cnorm  f32[1024]       0        4096   (biased +256)
//   cnts   int[4]          4096     16     ([0]=pair+triple, [1]=rescan)
//   arena  int[65536]      4112     262144 (pairs bottom-up, rescans top-down)
//   idxarr int[65536]      266256   262144 (triple px: bits 20-29 = 3rd cand)
//   cb16f  f16[1024*256]   528400   524288 (MFMA-fragment order)
#define WS_CNORM 0
#define WS_CNTS  4096
#define WS_ARENA 4112
#define WS_IDX   266256
#define WS_CB16  528400
#define WS_NEED  1052688u

__device__ __forceinline__ unsigned umn(unsigned a, unsigned b) { return a < b ? a : b; }
__device__ __forceinline__ unsigned umx(unsigned a, unsigned b) { return a > b ? a : b; }

// sorted-insert x into ascending quad (a1..a4)
__device__ __forceinline__ void ins4(unsigned& a1, unsigned& a2, unsigned& a3,
                                     unsigned& a4, unsigned x) {
    unsigned u1 = umx(a1, x);  a1 = umn(a1, x);
    unsigned u2 = umx(a2, u1); a2 = umn(a2, u1);
    unsigned u3 = umx(a3, u2); a3 = umn(a3, u2);
    a4 = umn(a4, u3);
}

__device__ __forceinline__ void gl16(const void* g, void* l) {
    __builtin_amdgcn_global_load_lds(
        (const __attribute__((address_space(1))) unsigned int*)g,
        (__attribute__((address_space(3))) unsigned int*)l, 16, 0, 0);
}

// ---- prep 1: cnorm (+256 bias) and zero counters. wave per codebook row.
__global__ __launch_bounds__(256) void vq_prep_cnorm(const float* __restrict__ cb,
                                                     float* __restrict__ cnorm,
                                                     int* __restrict__ cnts) {
    if (blockIdx.x == 0 && threadIdx.x < 4) cnts[threadIdx.x] = 0;
    const int lane = threadIdx.x & 63;
    const int k    = blockIdx.x * 4 + (threadIdx.x >> 6);
    float4 v = *reinterpret_cast<const float4*>(&cb[(size_t)k * C_DIM + 4 * lane]);
    float s = v.x * v.x + v.y * v.y + v.z * v.z + v.w * v.w;
#pragma unroll
    for (int m = 1; m < 64; m <<= 1) s += __shfl_xor(s, m, 64);
    if (lane == 0) cnorm[k] = s + 256.f;
}

// ---- prep 2: codebook -> fp16 in MFMA-fragment order.
// slot s = ((kt*4 + ct)*8 + kk)*64 + l holds 8 f16:
//   element j: cb[kt*64 + ct*16 + (l&15)][kk*32 + (l>>4)*8 + j]
__global__ __launch_bounds__(256) void vq_prep_cbf(const float* __restrict__ cb,
                                                   f16* __restrict__ cb16f) {
    int s  = blockIdx.x * 256 + threadIdx.x;     // 0..32767
    int l  = s & 63;
    int kk = (s >> 6) & 7;
    int ct = (s >> 9) & 3;
    int kt = s >> 11;
    int code = kt * 64 + ct * 16 + (l & 15);
    int k0   = kk * 32 + (l >> 4) * 8;
    const float* row = cb + (size_t)code * C_DIM + k0;
    float4 a = *reinterpret_cast<const float4*>(row);
    float4 b = *reinterpret_cast<const float4*>(row + 4);
    f16x8 h;
    h[0] = (f16)a.x; h[1] = (f16)a.y; h[2] = (f16)a.z; h[3] = (f16)a.w;
    h[4] = (f16)b.x; h[5] = (f16)b.y; h[6] = (f16)b.z; h[7] = (f16)b.w;
    *reinterpret_cast<f16x8*>(&cb16f[(size_t)s * 8]) = h;
}

// ---- main kernel: block = 128 px (4 waves x 32 px disjoint) x 1024 codes.
// A (pixels) in registers; Cs double-buffered, staged via global_load_lds
// one tile ahead (stage-next -> compute-cur -> barrier; T3 2-phase recipe).
__global__ __launch_bounds__(256, 2) void vq_mfma_kernel(const float* __restrict__ z,
                                                         const f16* __restrict__ cb16f,
                                                         const float* __restrict__ cnorm,
                                                         int* __restrict__ cnts,
                                                         int* __restrict__ arena,
                                                         int* __restrict__ idxarr) {
    __shared__ __align__(16) f16 CS[2][16384];   // 64 KB double buffer
    __shared__ float cns[K_CODES];               // 4 KB

    const int t    = threadIdx.x;
    const int bid  = blockIdx.x;
    const int b    = bid >> 3;
    const int hw0  = (bid & 7) << 7;
    const size_t zbase = (size_t)b * (C_DIM * HW) + hw0;

    const int lane = t & 63;
    const int w    = t >> 6;
    const int l15  = lane & 15;
    const int l4   = lane >> 4;

#pragma unroll
    for (int r = 0; r < 4; ++r) cns[t + 256 * r] = cnorm[t + 256 * r];

    // ---- A prologue: overlay fp32 staging buffer on the CS region (33 KB).
    float* xs = reinterpret_cast<float*>(&CS[0][0]);
    f16x8 af[2][8];
#pragma unroll
    for (int cc = 0; cc < 4; ++cc) {
        __syncthreads();
#pragma unroll
        for (int i = 0; i < 8; ++i) {
            int id  = t + 256 * i;          // 0..2047
            int c   = id >> 5;              // 0..63
            int px4 = (id & 31) << 2;       // 0..124
            float4 v = *reinterpret_cast<const float4*>(
                &z[zbase + (size_t)(cc * 64 + c) * HW + px4]);
            float* xr = &xs[c * 129 + px4];
            xr[0] = v.x; xr[1] = v.y; xr[2] = v.z; xr[3] = v.w;
        }
        __syncthreads();
#pragma unroll
        for (int kkl = 0; kkl < 2; ++kkl) {
#pragma unroll
            for (int tile = 0; tile < 2; ++tile) {
                int px    = w * 32 + tile * 16 + l15;
                int cbase = kkl * 32 + l4 * 8;
                f16x8 h;
#pragma unroll
                for (int j = 0; j < 8; ++j)
                    h[j] = (f16)xs[(cbase + j) * 129 + px];
                af[tile][cc * 2 + kkl] = h;
            }
        }
    }
    __syncthreads();   // prologue reads done before CS[0] is staged

    unsigned k1[8], k2[8], k3[8], k4[8];
#pragma unroll
    for (int s = 0; s < 8; ++s) { k1[s] = k2[s] = k3[s] = k4[s] = 0xFFFFFFFFu; }

    // ---- stage tile 0, then pipelined main loop: one barrier per tile.
    {
        const f16* src = cb16f;
#pragma unroll
        for (int r = 0; r < 8; ++r) {
            int slot = r * 256 + t;
            gl16(src + (size_t)slot * 8, &CS[0][slot * 8]);
        }
    }
    __syncthreads();   // vmcnt(0) drain: CS[0] ready

    for (int kt = 0; kt < 16; ++kt) {
        const int cur = kt & 1;
        if (kt < 15) {   // issue next-tile stage first; hides under compute
            const f16* src = cb16f + (size_t)(kt + 1) * 16384;
#pragma unroll
            for (int r = 0; r < 8; ++r) {
                int slot = r * 256 + t;
                gl16(src + (size_t)slot * 8, &CS[cur ^ 1][slot * 8]);
            }
        }

        f32x4 acc[2][4];
#pragma unroll
        for (int i = 0; i < 2; ++i)
#pragma unroll
            for (int j = 0; j < 4; ++j) acc[i][j] = (f32x4)0.f;

#pragma unroll
        for (int kk = 0; kk < 8; ++kk) {
            f16x8 b0 = *reinterpret_cast<const f16x8*>(&CS[cur][((0 * 8 + kk) * 64 + lane) * 8]);
            f16x8 b1 = *reinterpret_cast<const f16x8*>(&CS[cur][((1 * 8 + kk) * 64 + lane) * 8]);
            f16x8 b2 = *reinterpret_cast<const f16x8*>(&CS[cur][((2 * 8 + kk) * 64 + lane) * 8]);
            f16x8 b3 = *reinterpret_cast<const f16x8*>(&CS[cur][((3 * 8 + kk) * 64 + lane) * 8]);
#pragma unroll
            for (int tile = 0; tile < 2; ++tile) {
                acc[tile][0] = __builtin_amdgcn_mfma_f32_16x16x32_f16(af[tile][kk], b0, acc[tile][0], 0, 0, 0);
                acc[tile][1] = __builtin_amdgcn_mfma_f32_16x16x32_f16(af[tile][kk], b1, acc[tile][1], 0, 0, 0);
                acc[tile][2] = __builtin_amdgcn_mfma_f32_16x16x32_f16(af[tile][kk], b2, acc[tile][2], 0, 0, 0);
                acc[tile][3] = __builtin_amdgcn_mfma_f32_16x16x32_f16(af[tile][kk], b3, acc[tile][3], 0, 0, 0);
            }
        }

        // keys: d = cnorm+256 - 2 x.c ; truncate low 10 bits, pack code index
        const int ktbase = kt * 64;
#pragma unroll
        for (int ct = 0; ct < 4; ++ct) {
            int code  = ktbase + ct * 16 + l15;
            float cnv = cns[code];
#pragma unroll
            for (int tile = 0; tile < 2; ++tile) {
#pragma unroll
                for (int reg = 0; reg < 4; ++reg) {
                    float d = fmaf(-2.f, acc[tile][ct][reg], cnv);
                    unsigned key = (__float_as_uint(d) & 0xFFFFFC00u) | (unsigned)code;
                    int s = tile * 4 + reg;
                    ins4(k1[s], k2[s], k3[s], k4[s], key);
                }
            }
        }

        __syncthreads();   // drains next-tile stage; all readers of CS[cur] done
    }

    // ---- reduce top-4 across the 16 code-lanes (same l4 group); classify.
#pragma unroll
    for (int s = 0; s < 8; ++s) {
        unsigned a1 = k1[s], a2 = k2[s], a3 = k3[s], a4 = k4[s];
#pragma unroll
        for (int m = 1; m < 16; m <<= 1) {
            unsigned b1 = __shfl_xor(a1, m, 16);
            unsigned b2 = __shfl_xor(a2, m, 16);
            unsigned b3 = __shfl_xor(a3, m, 16);
            unsigned b4 = __shfl_xor(a4, m, 16);
            ins4(a1, a2, a3, a4, b1);
            ins4(a1, a2, a3, a4, b2);
            ins4(a1, a2, a3, a4, b3);
            ins4(a1, a2, a3, a4, b4);
        }
        if (l15 == 0) {
            int px = (w << 5) + ((s >> 2) << 4) + (l4 << 2) + (s & 3);
            int gp = (bid << 7) + px;
            float v1 = __uint_as_float(a1 & 0xFFFFFC00u);
            float v2 = __uint_as_float(a2 & 0xFFFFFC00u);
            float v3 = __uint_as_float(a3 & 0xFFFFFC00u);
            float v4 = __uint_as_float(a4 & 0xFFFFFC00u);
            int i1 = (int)(a1 & 1023u);
            int i2 = (int)(a2 & 1023u);
            int i3 = (int)(a3 & 1023u);
            int iv = i1;
            if (v4 - v1 < EPS) {                 // >=4 candidates: full rescan
                int p = atomicAdd(&cnts[1], 1);
                arena[65535 - p] = gp;
            } else if (v3 - v1 < EPS) {          // 3 candidates
                int p = atomicAdd(&cnts[0], 1);
                arena[p] = gp | (i2 << 16) | (int)0x80000000u;
                iv = i1 | (i3 << 20);
            } else if (v2 - v1 < EPS) {          // 2 candidates
                int p = atomicAdd(&cnts[0], 1);
                arena[p] = gp | (i2 << 16);
            }
            idxarr[gp] = iv;
        }
    }
}

// ---- refine: exact fp32 compare of 2 or 3 candidates; one wave per entry.
__global__ __launch_bounds__(256) void vq_refine_kernel(const float* __restrict__ z,
                                                        const float* __restrict__ cb,
                                                        const float* __restrict__ cnorm,
                                                        const int* __restrict__ cnts,
                                                        const int* __restrict__ arena,
                                                        int* __restrict__ idxarr) {
    const int lane = threadIdx.x & 63;
    const int wid  = (blockIdx.x * 256 + threadIdx.x) >> 6;
    const int nw   = gridDim.x * 4;
    const int nb   = cnts[0];
    for (int i = wid; i < nb; i += nw) {
        int e  = arena[i];
        int gp = e & 0xFFFF;
        int j2 = (e >> 16) & 1023;
        bool tri = e < 0;
        int iv = idxarr[gp];
        int c1 = iv & 1023;
        int j3 = (iv >> 20) & 1023;
        int b = gp >> 10, hw = gp & 1023;
        const float* xb = z + (size_t)b * (C_DIM * HW) + hw;
        float x0 = xb[(size_t)(4 * lane + 0) * HW];
        float x1 = xb[(size_t)(4 * lane + 1) * HW];
        float x2 = xb[(size_t)(4 * lane + 2) * HW];
        float x3 = xb[(size_t)(4 * lane + 3) * HW];
        float4 r1 = *reinterpret_cast<const float4*>(&cb[(size_t)c1 * C_DIM + 4 * lane]);
        float4 r2 = *reinterpret_cast<const float4*>(&cb[(size_t)j2 * C_DIM + 4 * lane]);
        float s1 = fmaf(x0, r1.x, fmaf(x1, r1.y, fmaf(x2, r1.z, x3 * r1.w)));
        float s2 = fmaf(x0, r2.x, fmaf(x1, r2.y, fmaf(x2, r2.z, x3 * r2.w)));
        float s3 = 0.f;
        if (tri) {
            float4 r3 = *reinterpret_cast<const float4*>(&cb[(size_t)j3 * C_DIM + 4 * lane]);
            s3 = fmaf(x0, r3.x, fmaf(x1, r3.y, fmaf(x2, r3.z, x3 * r3.w)));
        }
#pragma unroll
        for (int m = 1; m < 64; m <<= 1) {
            s1 += __shfl_xor(s1, m, 64);
            s2 += __shfl_xor(s2, m, 64);
            s3 += __shfl_xor(s3, m, 64);
        }
        if (lane == 0) {
            float d1 = fmaf(-2.f, s1, cnorm[c1]);
            float d2 = fmaf(-2.f, s2, cnorm[j2]);
            int bi = c1; float bd = d1;
            if (d2 < bd || (d2 == bd && j2 < bi)) { bd = d2; bi = j2; }
            if (tri) {
                float d3 = fmaf(-2.f, s3, cnorm[j3]);
                if (d3 < bd || (d3 == bd && j3 < bi)) { bd = d3; bi = j3; }
            }
            idxarr[gp] = bi;
        }
    }
}

// ---- rescan: exact fp32 argmin over all 1024 codes; 256-thread block per px.
// Each thread owns 4 codes {t, t+256, t+512, t+768}; unroll-8 row streaming.
__global__ __launch_bounds__(256) void vq_rescan_kernel(const float* __restrict__ z,
                                                        const float* __restrict__ cb,
                                                        const float* __restrict__ cnorm,
                                                        const int* __restrict__ cnts,
                                                        const int* __restrict__ arena,
                                                        int* __restrict__ idxarr) {
    __shared__ float xw[C_DIM];
    __shared__ float rdv[4];
    __shared__ int   rdi[4];
    const int t = threadIdx.x;
    const int nr = cnts[1];
    for (int q = blockIdx.x; q < nr; q += gridDim.x) {
        int gp = arena[65535 - q];
        int b = gp >> 10, hw = gp & 1023;
        __syncthreads();   // previous iteration's readers of xw/rdv/rdi done
        xw[t] = z[(size_t)b * (C_DIM * HW) + (size_t)t * HW + hw];
        __syncthreads();
        float bd = 3.4e38f; int bi = 0;
#pragma unroll
        for (int rr = 0; rr < 4; ++rr) {
            int k = rr * 256 + t;   // ascending per thread -> strict < keeps lowest
            const float4* cr = reinterpret_cast<const float4*>(cb + (size_t)k * C_DIM);
            float s0 = 0.f, s1 = 0.f, s2 = 0.f, s3 = 0.f;
#pragma unroll 8
            for (int d4 = 0; d4 < 64; ++d4) {
                float4 cv = cr[d4];
                s0 = fmaf(xw[4 * d4 + 0], cv.x, s0);
                s1 = fmaf(xw[4 * d4 + 1], cv.y, s1);
                s2 = fmaf(xw[4 * d4 + 2], cv.z, s2);
                s3 = fmaf(xw[4 * d4 + 3], cv.w, s3);
            }
            float dist = fmaf(-2.f, (s0 + s1) + (s2 + s3), cnorm[k]);
            if (dist < bd) { bd = dist; bi = k; }
        }
        // wave reduce (64) with lowest-index tie-break
#pragma unroll
        for (int m = 1; m < 64; m <<= 1) {
            float od = __shfl_xor(bd, m, 64);
            int   oi = __shfl_xor(bi, m, 64);
            if (od < bd || (od == bd && oi < bi)) { bd = od; bi = oi; }
        }
        if ((t & 63) == 0) { rdv[t >> 6] = bd; rdi[t >> 6] = bi; }
        __syncthreads();
        if (t == 0) {
            float fb = rdv[0]; int fi = rdi[0];
#pragma unroll
            for (int u = 1; u < 4; ++u) {
                if (rdv[u] < fb || (rdv[u] == fb && rdi[u] < fi)) { fb = rdv[u]; fi = rdi[u]; }
            }
            idxarr[gp] = fi;
        }
    }
}

// ---- gather final codes, write both outputs as float4.
__global__ __launch_bounds__(256) void vq_gather_kernel(const float* __restrict__ cb,
                                                        const int* __restrict__ idxarr,
                                                        float* __restrict__ out) {
    __shared__ int idxs[256];
    const int t = threadIdx.x;
    idxs[t] = idxarr[blockIdx.x * 256 + t];
    __syncthreads();
    const int b     = blockIdx.x >> 2;
    const int hw0   = (blockIdx.x & 3) << 8;
    const int px4   = (t & 63) << 2;
    const int cbase = t >> 6;
    const float* r0 = cb + (size_t)idxs[px4 + 0] * C_DIM;
    const float* r1 = cb + (size_t)idxs[px4 + 1] * C_DIM;
    const float* r2 = cb + (size_t)idxs[px4 + 2] * C_DIM;
    const float* r3 = cb + (size_t)idxs[px4 + 3] * C_DIM;
    const size_t obase = (size_t)b * (C_DIM * HW) + hw0 + px4;
#pragma unroll 8
    for (int c = cbase; c < C_DIM; c += 4) {
        float4 v = { r0[c], r1[c], r2[c], r3[c] };
        *reinterpret_cast<float4*>(&out[obase + (size_t)c * HW]) = v;
        *reinterpret_cast<float4*>(&out[obase + (size_t)c * HW + OUT_OFF]) = v;
    }
}

// ---------------- fallback (round-1 exact fp32 kernels, needs only 4KB ws) ----
__global__ __launch_bounds__(256) void vq_cnorm_kernel(const float* __restrict__ cb,
                                                       float* __restrict__ cnorm) {
    int k = blockIdx.x * 256 + threadIdx.x;
    if (k >= K_CODES) return;
    const float4* row = reinterpret_cast<const float4*>(cb + (size_t)k * C_DIM);
    float s = 0.f;
#pragma unroll 8
    for (int u = 0; u < C_DIM / 4; ++u) {
        float4 v = row[u];
        s += v.x * v.x + v.y * v.y + v.z * v.z + v.w * v.w;
    }
    cnorm[k] = s;
}

__global__ __launch_bounds__(256, 4) void vq_main_kernel(const float* __restrict__ z,
                                                         const float* __restrict__ cb,
                                                         const float* __restrict__ cnorm,
                                                         float* __restrict__ out) {
    __shared__ float Xs[64][64];
    __shared__ float Bs[64][68];
    __shared__ float cns[K_CODES];
    __shared__ int   idxs[64];

    const int t  = threadIdx.x;
    const int tx = t & 15;
    const int ty = t >> 4;
    const int b   = blockIdx.x >> 4;
    const int hw0 = (blockIdx.x & 15) << 6;
    const size_t zbase = (size_t)b * (C_DIM * HW) + hw0;

#pragma unroll
    for (int r = 0; r < 4; ++r) cns[t + 256 * r] = cnorm[t + 256 * r];

    float best[4];
    int   bidx[4];
#pragma unroll
    for (int i = 0; i < 4; ++i) { best[i] = 3.4e38f; bidx[i] = 0; }

    for (int kt = 0; kt < 16; ++kt) {
        float acc[4][4];
#pragma unroll
        for (int i = 0; i < 4; ++i)
#pragma unroll
            for (int j = 0; j < 4; ++j) acc[i][j] = 0.f;

        for (int cc = 0; cc < 4; ++cc) {
            const int c0g = cc * 64;
            __syncthreads();
#pragma unroll
            for (int r = 0; r < 4; ++r) {
                int c   = (t >> 4) + 16 * r;
                int px4 = (t & 15) * 4;
                *reinterpret_cast<float4*>(&Xs[c][px4]) =
                    *reinterpret_cast<const float4*>(&z[zbase + (size_t)(c0g + c) * HW + px4]);
                int k  = (t >> 4) + 16 * r;
                int c4 = (t & 15) * 4;
                *reinterpret_cast<float4*>(&Bs[k][c4]) =
                    *reinterpret_cast<const float4*>(&cb[(size_t)(kt * 64 + k) * C_DIM + c0g + c4]);
            }
            __syncthreads();

#pragma unroll
            for (int c0 = 0; c0 < 64; c0 += 4) {
                float4 xv[4], bv[4];
#pragma unroll
                for (int s = 0; s < 4; ++s)
                    xv[s] = *reinterpret_cast<const float4*>(&Xs[c0 + s][4 * ty]);
#pragma unroll
                for (int j = 0; j < 4; ++j)
                    bv[j] = *reinterpret_cast<const float4*>(&Bs[16 * j + tx][c0]);
#pragma unroll
                for (int i = 0; i < 4; ++i) {
#pragma unroll
                    for (int j = 0; j < 4; ++j) {
                        float xi0 = (i == 0) ? xv[0].x : (i == 1) ? xv[0].y : (i == 2) ? xv[0].z : xv[0].w;
                        float xi1 = (i == 0) ? xv[1].x : (i == 1) ? xv[1].y : (i == 2) ? xv[1].z : xv[1].w;
                        float xi2 = (i == 0) ? xv[2].x : (i == 1) ? xv[2].y : (i == 2) ? xv[2].z : xv[2].w;
                        float xi3 = (i == 0) ? xv[3].x : (i == 1) ? xv[3].y : (i == 2) ? xv[3].z : xv[3].w;
                        acc[i][j] = fmaf(xi0, bv[j].x,
                                    fmaf(xi1, bv[j].y,
                                    fmaf(xi2, bv[j].z,
                                    fmaf(xi3, bv[j].w, acc[i][j]))));
                    }
                }
            }
        }

#pragma unroll
        for (int j = 0; j < 4; ++j) {
            int kg = kt * 64 + 16 * j + tx;
            float cnv = cns[kg];
#pragma unroll
            for (int i = 0; i < 4; ++i) {
                float d = cnv - 2.f * acc[i][j];
                if (d < best[i]) { best[i] = d; bidx[i] = kg; }
            }
        }
    }

#pragma unroll
    for (int i = 0; i < 4; ++i) {
#pragma unroll
        for (int off = 8; off >= 1; off >>= 1) {
            float od = __shfl_xor(best[i], off, 16);
            int   oi = __shfl_xor(bidx[i], off, 16);
            if (od < best[i] || (od == best[i] && oi < bidx[i])) { best[i] = od; bidx[i] = oi; }
        }
        if (tx == 0) idxs[4 * ty + i] = bidx[i];
    }
    __syncthreads();

    const int px = t & 63;
    const int c0 = t >> 6;
    const int code = idxs[px];
    const float* crow = cb + (size_t)code * C_DIM;
    const size_t obase = (size_t)b * (C_DIM * HW) + hw0 + px;
#pragma unroll 4
    for (int c = c0; c < C_DIM; c += 4) {
        float v = crow[c];
        out[obase + (size_t)c * HW] = v;
        out[obase + (size_t)c * HW + OUT_OFF] = v;
    }
}

extern "C" void kernel_launch(void* const* d_in, const int* in_sizes, int n_in,
                              void* d_out, int out_size, void* d_ws, size_t ws_size,
                              hipStream_t stream) {
    const float* z  = (const float*)d_in[0];
    const float* cb = (const float*)d_in[1];
    float* out = (float*)d_out;

    float* cnorm  = (float*)((char*)d_ws + WS_CNORM);
    int*   cnts   = (int*)((char*)d_ws + WS_CNTS);
    int*   arena  = (int*)((char*)d_ws + WS_ARENA);
    int*   idxarr = (int*)((char*)d_ws + WS_IDX);
    f16*   cb16f  = (f16*)((char*)d_ws + WS_CB16);

    if (ws_size >= WS_NEED) {
        vq_prep_cnorm<<<K_CODES / 4, 256, 0, stream>>>(cb, cnorm, cnts);
        vq_prep_cbf<<<128, 256, 0, stream>>>(cb, cb16f);
        vq_mfma_kernel<<<512, 256, 0, stream>>>(z, cb16f, cnorm, cnts, arena, idxarr);
        vq_refine_kernel<<<256, 256, 0, stream>>>(z, cb, cnorm, cnts, arena, idxarr);
        vq_rescan_kernel<<<128, 256, 0, stream>>>(z, cb, cnorm, cnts, arena, idxarr);
        vq_gather_kernel<<<256, 256, 0, stream>>>(cb, idxarr, out);
    } else {
        vq_cnorm_kernel<<<K_CODES / 256, 256, 0, stream>>>(cb, cnorm);
        vq_main_kernel<<<1024, 256, 0, stream>>>(z, cb, cnorm, out);
    }
}